// Round 8
// baseline (20263.412 us; speedup 1.0000x reference)
//
#include <hip/hip_runtime.h>

// ReverseLSTMLayer: T=1024, B=32, I=1024, H=1024, fp32 in/out.
// d_out layout: outputs [T*B*H] | h_fin [B*H] | c_fin [B*H].
//
// Round 8: persistent kernel (256 blocks x 512 threads, 1 block/CU via 144KB
// LDS). W hi/lo fragment-major LDS-resident; c in registers; x reg-prefetch.
// NEW vs round 7:
//  - h exchange buffer TRANSPOSED: hT[col][batch] packed uint(bf16hi|lo).
//    Producer block writes 512 contiguous bytes (coalesced CP writes, was
//    128 scattered dwords at 4KB stride). Consumer reads 64B-coalesced.
//  - Monotonic-counter barrier (no resets, no releases): group fetch_add ->
//    root fetch_add -> root-finisher broadcast-stores step# to 16 group
//    lines -> all waves poll own group line independently.
//  - x-part MFMAs + x prefetch issued BEFORE the poll (overlap the wait).
//  - Branchless tanh via __expf (replaces libm tanhf on critical path).
// Split-bf16 3-pass MFMA numerics (proven absmax 0.0039).

constexpr int T_STEPS = 1024;
constexpr int BATCH   = 32;
constexpr int IN_DIM  = 1024;
constexpr int HID     = 1024;
constexpr int BH      = BATCH * HID;   // 32768
constexpr int NBLK    = 256;

typedef __attribute__((ext_vector_type(8))) short  short8;
typedef __attribute__((ext_vector_type(4))) float  f32x4;

__device__ __forceinline__ unsigned short f2bf(float f) {
    union { float f; unsigned u; } x; x.f = f;
    unsigned r = (x.u + 0x7fffu + ((x.u >> 16) & 1u)) >> 16;
    return (unsigned short)r;
}
__device__ __forceinline__ float bf2f(unsigned short h) {
    union { unsigned u; float f; } x; x.u = ((unsigned)h) << 16;
    return x.f;
}
__device__ __forceinline__ f32x4 mfma16(short8 a, short8 b, f32x4 c) {
    return __builtin_amdgcn_mfma_f32_16x16x32_bf16(a, b, c, 0, 0, 0);
}
__device__ __forceinline__ unsigned rmw_add(unsigned* p, unsigned v) {
    return __hip_atomic_fetch_add(p, v, __ATOMIC_RELAXED, __HIP_MEMORY_SCOPE_AGENT);
}
__device__ __forceinline__ unsigned flag_ld(const unsigned* p) {
    return __hip_atomic_load(p, __ATOMIC_RELAXED, __HIP_MEMORY_SCOPE_AGENT);
}
__device__ __forceinline__ float sigmoid_fast(float x) {
    return 1.0f / (1.0f + __expf(-x));
}
__device__ __forceinline__ float tanh_fast(float x) {
    const float t = __expf(-2.0f * fabsf(x));
    const float r = (1.0f - t) / (1.0f + t);
    return copysignf(r, x);
}

// ---------------- one-time converters ----------------

__global__ void convert_split(const float* __restrict__ src,
                              unsigned short* __restrict__ hi,
                              unsigned short* __restrict__ lo, int n4) {
    for (int i = blockIdx.x * blockDim.x + threadIdx.x; i < n4;
         i += gridDim.x * blockDim.x) {
        const float4 v = ((const float4*)src)[i];
        ushort4 h, l;
        float t;
        h.x = f2bf(v.x); t = v.x - bf2f(h.x); l.x = f2bf(t);
        h.y = f2bf(v.y); t = v.y - bf2f(h.y); l.y = f2bf(t);
        h.z = f2bf(v.z); t = v.z - bf2f(h.z); l.z = f2bf(t);
        h.w = f2bf(v.w); t = v.w - bf2f(h.w); l.w = f2bf(t);
        ((ushort4*)hi)[i] = h;
        ((ushort4*)lo)[i] = l;
    }
}

// Wpk[blk][half(hi=0,lo=1)][kstep 0..63][lane 0..63][8 elems].
// (blk, lane): m=lane&15, kg=(lane>>4)*8, row=(m>>2)*1024+blk*4+(m&3),
// k = kstep*32+kg; k<1024 -> W_ih, else W_hh.
__global__ void pack_W(const float* __restrict__ W_ih,
                       const float* __restrict__ W_hh,
                       unsigned short* __restrict__ Wpk) {
    const int i = blockIdx.x * blockDim.x + threadIdx.x;   // 0 .. 2,097,151
    const int lane = i & 63;
    const int s    = (i >> 6) & 63;
    const int half = (i >> 12) & 1;
    const int blk  = i >> 13;
    if (blk >= NBLK) return;
    const int m   = lane & 15;
    const int kg  = (lane >> 4) << 3;
    const int row = ((m >> 2) << 10) + (blk << 2) + (m & 3);
    const int k   = (s << 5) + kg;
    const float* src = (k < IN_DIM) ? (W_ih + (size_t)row * IN_DIM + k)
                                    : (W_hh + (size_t)row * HID + (k - IN_DIM));
    unsigned short v[8];
    #pragma unroll
    for (int e = 0; e < 8; ++e) {
        const float f = src[e];
        const unsigned short h = f2bf(f);
        v[e] = half ? f2bf(f - bf2f(h)) : h;
    }
    ushort4* dst = (ushort4*)(Wpk + (size_t)i * 8);
    dst[0] = make_ushort4(v[0], v[1], v[2], v[3]);
    dst[1] = make_ushort4(v[4], v[5], v[6], v[7]);
}

// h0 pack TRANSPOSED (hT[col][b]), bias combine, barrier reset (4096 uints).
__global__ void prep_state(const float* __restrict__ h0,
                           const float* __restrict__ b_ih,
                           const float* __restrict__ b_hh,
                           unsigned* __restrict__ hT,
                           float* __restrict__ bias,
                           unsigned* __restrict__ bar) {
    const int i = blockIdx.x * blockDim.x + threadIdx.x;
    if (i < BH) {
        const int b   = i >> 10;        // batch
        const int col = i & 1023;       // hidden col
        const float v = h0[i];
        const unsigned short hh = f2bf(v);
        const unsigned short hl = f2bf(v - bf2f(hh));
        hT[col * BATCH + b] = ((unsigned)hh << 16) | (unsigned)hl;
    }
    if (i < 4 * HID) bias[i] = b_ih[i] + b_hh[i];
    if (i < 4096) bar[i] = 0u;
}

// ---------------- persistent LSTM scan ----------------
// Dynamic LDS: [0,128KiB) W fragments; [128KiB,144KiB) reduce float[16][256].
// bar[]: gcnt[g]=bar[g*64] (g=blk&15), gph[g]=bar[1024+g*64], rcnt=bar[2048].
// All counters MONOTONIC (no resets): after step i completes, gcnt[g]=16(i+1),
// rcnt=16(i+1), gph[g]=i+1 (stored by root-finisher broadcast).
__global__ __launch_bounds__(512, 2) void lstm_persistent(
    const unsigned short* __restrict__ x_hi,   // [T][32][1024]
    const unsigned short* __restrict__ x_lo,
    const unsigned short* __restrict__ Wpk,    // [256][2][64][64][8]
    unsigned* __restrict__ hA,                 // hT[1024][32] packed
    unsigned* __restrict__ hB,
    const float* __restrict__ bias,            // [4096]
    const float* __restrict__ c0,              // [32][1024]
    float* __restrict__ out,
    unsigned* __restrict__ bar)
{
    extern __shared__ unsigned char smem[];
    float* red = (float*)(smem + 131072);

    const int tid  = threadIdx.x;
    const int wave = tid >> 6;
    const int lane = tid & 63;
    const int blk  = blockIdx.x;

    // One-time: copy this block's 128 KiB W slice into LDS (coalesced).
    {
        const uint4* src = (const uint4*)Wpk + (size_t)blk * 8192;
        uint4* dst = (uint4*)smem;
        #pragma unroll
        for (int r = 0; r < 16; ++r) dst[r * 512 + tid] = src[r * 512 + tid];
    }

    const int m16    = lane & 15;
    const int kg     = (lane >> 4) << 3;
    const int off_b0 = m16 * HID + (wave << 7) + kg;   // x frag base, b 0-15
    const int off_b1 = off_b0 + 16 * HID;              // b 16-31
    const int wbyte  = lane << 4;

    // Per-thread persistent epilogue state (tid < 128): c + bias.
    float c_reg = 0.f;
    float bias_reg[4] = {0.f, 0.f, 0.f, 0.f};
    const int b_own   = tid >> 2;
    const int jj      = tid & 3;
    const int col_own = (blk << 2) + jj;
    const int idx_own = b_own * HID + col_own;
    if (tid < 128) {
        #pragma unroll
        for (int g = 0; g < 4; ++g) bias_reg[g] = bias[g * HID + col_own];
        c_reg = c0[idx_own];
    }

    unsigned* const gcnt   = bar + ((blk & 15) * 64);
    unsigned* const gph_my = bar + 1024 + ((blk & 15) * 64);
    unsigned* const rcnt   = bar + 2048;

    __syncthreads();

    unsigned* hin  = hA;
    unsigned* hout = hB;

    // Prefetch x fragments for the first step.
    short8 pxh0[4], pxh1[4], pxl0[4], pxl1[4];
    {
        const unsigned short* xh = x_hi + (size_t)(T_STEPS - 1) * BH;
        const unsigned short* xl = x_lo + (size_t)(T_STEPS - 1) * BH;
        #pragma unroll
        for (int sq = 0; sq < 4; ++sq) {
            pxh0[sq] = *(const short8*)(xh + off_b0 + (sq << 5));
            pxh1[sq] = *(const short8*)(xh + off_b1 + (sq << 5));
            pxl0[sq] = *(const short8*)(xl + off_b0 + (sq << 5));
            pxl1[sq] = *(const short8*)(xl + off_b1 + (sq << 5));
        }
    }

    for (int i = 0; i < T_STEPS; ++i) {
        const int t = T_STEPS - 1 - i;

        f32x4 acc0 = {0.f, 0.f, 0.f, 0.f};
        f32x4 acc1 = {0.f, 0.f, 0.f, 0.f};

        // x-part MFMAs (independent of h -> overlaps the barrier wait).
        #pragma unroll
        for (int sq = 0; sq < 4; ++sq) {
            const int s = (wave << 2) + sq;
            const short8 whi = *(const short8*)(smem + (size_t)s * 1024 + wbyte);
            const short8 wlo = *(const short8*)(smem + (size_t)(64 + s) * 1024 + wbyte);
            acc0 = mfma16(whi, pxh0[sq], acc0);
            acc0 = mfma16(whi, pxl0[sq], acc0);
            acc0 = mfma16(wlo, pxh0[sq], acc0);
            acc1 = mfma16(whi, pxh1[sq], acc1);
            acc1 = mfma16(whi, pxl1[sq], acc1);
            acc1 = mfma16(wlo, pxh1[sq], acc1);
        }

        // Issue next-step x prefetch (completes under h wait/compute).
        if (i + 1 < T_STEPS) {
            const unsigned short* xh = x_hi + (size_t)(t - 1) * BH;
            const unsigned short* xl = x_lo + (size_t)(t - 1) * BH;
            #pragma unroll
            for (int sq = 0; sq < 4; ++sq) {
                pxh0[sq] = *(const short8*)(xh + off_b0 + (sq << 5));
                pxh1[sq] = *(const short8*)(xh + off_b1 + (sq << 5));
                pxl0[sq] = *(const short8*)(xl + off_b0 + (sq << 5));
                pxl1[sq] = *(const short8*)(xl + off_b1 + (sq << 5));
            }
        }

        // Wait for step i-1's h (each wave independently; uniform address ->
        // one transaction per poll). Then acquire-fence: drop stale h lines.
        if (i > 0) {
            while (flag_ld(gph_my) < (unsigned)i) __builtin_amdgcn_s_sleep(1);
            __builtin_amdgcn_fence(__ATOMIC_ACQUIRE, "agent");
        }

        // h loads (64B-coalesced per 16-lane group, cached) + h MFMAs.
        #pragma unroll
        for (int sq = 0; sq < 4; ++sq) {
            const int s = 32 + (wave << 2) + sq;
            const short8 whi = *(const short8*)(smem + (size_t)s * 1024 + wbyte);
            const short8 wlo = *(const short8*)(smem + (size_t)(64 + s) * 1024 + wbyte);
            const int kb = (wave << 7) + (sq << 5) + kg;
            unsigned d0[8], d1[8];
            #pragma unroll
            for (int e = 0; e < 8; ++e) {
                d0[e] = hin[(kb + e) * BATCH + m16];
                d1[e] = hin[(kb + e) * BATCH + 16 + m16];
            }
            short8 hh0, hl0, hh1, hl1;
            #pragma unroll
            for (int e = 0; e < 8; ++e) {
                hh0[e] = (short)(d0[e] >> 16); hl0[e] = (short)(d0[e] & 0xffffu);
                hh1[e] = (short)(d1[e] >> 16); hl1[e] = (short)(d1[e] & 0xffffu);
            }
            acc0 = mfma16(whi, hh0, acc0);
            acc0 = mfma16(whi, hl0, acc0);
            acc0 = mfma16(wlo, hh0, acc0);
            acc1 = mfma16(whi, hh1, acc1);
            acc1 = mfma16(whi, hl1, acc1);
            acc1 = mfma16(wlo, hh1, acc1);
        }

        // Cross-wave reduce. C/D layout (m89): col=lane&15, row=4*(lane>>4)+r.
        {
            const int arow = (lane >> 4) << 2;
            const int acol = lane & 15;
            #pragma unroll
            for (int r = 0; r < 4; ++r) {
                red[((wave << 1) + 0) * 256 + (arow + r) * 16 + acol] = acc0[r];
                red[((wave << 1) + 1) * 256 + (arow + r) * 16 + acol] = acc1[r];
            }
        }
        __syncthreads();

        if (tid < 128) {
            const int mt  = b_own >> 4;
            const int c16 = b_own & 15;
            float val[4];
            #pragma unroll
            for (int g = 0; g < 4; ++g) {
                const int rr = ((g << 2) + jj) * 16 + c16;
                float sacc = 0.f;
                #pragma unroll
                for (int w = 0; w < 8; ++w) sacc += red[((w << 1) + mt) * 256 + rr];
                val[g] = sacc + bias_reg[g];
            }
            const float ig = sigmoid_fast(val[0]);
            const float fg = sigmoid_fast(val[1]);
            const float gg = tanh_fast(val[2]);
            const float og = sigmoid_fast(val[3]);
            c_reg = fg * c_reg + ig * gg;
            const float h_new = og * tanh_fast(c_reg);
            out[(size_t)t * BH + idx_own] = h_new;               // cached
            const unsigned short hh = f2bf(h_new);
            const unsigned short hl = f2bf(h_new - bf2f(hh));
            const unsigned pk = ((unsigned)hh << 16) | (unsigned)hl;
            // Transposed, block-contiguous: addr = blk*128 + jj*32 + b_own.
            __hip_atomic_store(hout + col_own * BATCH + b_own, pk,
                               __ATOMIC_RELAXED, __HIP_MEMORY_SCOPE_AGENT);
            if (t == 0) out[(size_t)T_STEPS * BH + idx_own] = h_new;  // h_fin
        }

        // Drain all waves' stores (vmcnt=0 before s_barrier), then arrive.
        __syncthreads();
        if (tid == 0) {
            const unsigned a = rmw_add(gcnt, 1u);
            if ((a & 15u) == 15u) {               // last of group
                const unsigned r = rmw_add(rcnt, 1u);
                if ((r & 15u) == 15u) {           // last of grid: broadcast
                    #pragma unroll
                    for (int g = 0; g < 16; ++g)
                        __hip_atomic_store(bar + 1024 + g * 64, (unsigned)(i + 1),
                                           __ATOMIC_RELAXED,
                                           __HIP_MEMORY_SCOPE_AGENT);
                }
            }
        }
        // No trailing __syncthreads: each wave polls independently next step.

        unsigned* th = hin; hin = hout; hout = th;
    }

    if (tid < 128)
        out[(size_t)T_STEPS * BH + BH + idx_own] = c_reg;   // c_fin
}

// ---------------- fallback (round-1, known-good, slow) ----------------
__global__ __launch_bounds__(256) void lstm_step_fused(
    const float* __restrict__ x_t, const float* __restrict__ h_prev,
    const float* __restrict__ c_prev, float* __restrict__ c_out,
    float* __restrict__ h_out, const float* __restrict__ W_ih,
    const float* __restrict__ W_hh, const float* __restrict__ b_ih,
    const float* __restrict__ b_hh) {
    __shared__ float xs[IN_DIM];
    __shared__ float hs[HID];
    const int tid = threadIdx.x;
    const int b   = blockIdx.x >> 2;
    const int j   = ((blockIdx.x & 3) << 8) | tid;
    ((float4*)xs)[tid] = ((const float4*)(x_t    + (size_t)b * IN_DIM))[tid];
    ((float4*)hs)[tid] = ((const float4*)(h_prev + (size_t)b * HID))[tid];
    __syncthreads();
    float a0 = b_ih[j] + b_hh[j];
    float a1 = b_ih[HID + j] + b_hh[HID + j];
    float a2 = b_ih[2*HID + j] + b_hh[2*HID + j];
    float a3 = b_ih[3*HID + j] + b_hh[3*HID + j];
    {
        const float4* wi0 = (const float4*)(W_ih + (size_t)(0*HID + j) * IN_DIM);
        const float4* wi1 = (const float4*)(W_ih + (size_t)(1*HID + j) * IN_DIM);
        const float4* wi2 = (const float4*)(W_ih + (size_t)(2*HID + j) * IN_DIM);
        const float4* wi3 = (const float4*)(W_ih + (size_t)(3*HID + j) * IN_DIM);
        const float4* xs4 = (const float4*)xs;
        #pragma unroll 4
        for (int k = 0; k < IN_DIM / 4; ++k) {
            const float4 xv = xs4[k]; float4 w;
            w = wi0[k]; a0 += xv.x*w.x + xv.y*w.y + xv.z*w.z + xv.w*w.w;
            w = wi1[k]; a1 += xv.x*w.x + xv.y*w.y + xv.z*w.z + xv.w*w.w;
            w = wi2[k]; a2 += xv.x*w.x + xv.y*w.y + xv.z*w.z + xv.w*w.w;
            w = wi3[k]; a3 += xv.x*w.x + xv.y*w.y + xv.z*w.z + xv.w*w.w;
        }
    }
    {
        const float4* wh0 = (const float4*)(W_hh + (size_t)(0*HID + j) * HID);
        const float4* wh1 = (const float4*)(W_hh + (size_t)(1*HID + j) * HID);
        const float4* wh2 = (const float4*)(W_hh + (size_t)(2*HID + j) * HID);
        const float4* wh3 = (const float4*)(W_hh + (size_t)(3*HID + j) * HID);
        const float4* hs4 = (const float4*)hs;
        #pragma unroll 4
        for (int k = 0; k < HID / 4; ++k) {
            const float4 hv = hs4[k]; float4 w;
            w = wh0[k]; a0 += hv.x*w.x + hv.y*w.y + hv.z*w.z + hv.w*w.w;
            w = wh1[k]; a1 += hv.x*w.x + hv.y*w.y + hv.z*w.z + hv.w*w.w;
            w = wh2[k]; a2 += hv.x*w.x + hv.y*w.y + hv.z*w.z + hv.w*w.w;
            w = wh3[k]; a3 += hv.x*w.x + hv.y*w.y + hv.z*w.z + hv.w*w.w;
        }
    }
    const float ig = 1.0f / (1.0f + __expf(-a0));
    const float fg = 1.0f / (1.0f + __expf(-a1));
    const float gg = tanhf(a2);
    const float og = 1.0f / (1.0f + __expf(-a3));
    const size_t idx = (size_t)b * HID + j;
    const float c_new = fg * c_prev[idx] + ig * gg;
    c_out[idx] = c_new;
    h_out[idx] = og * tanhf(c_new);
}

__global__ void lstm_finalize(const float* __restrict__ h_fin_src,
                              const float* __restrict__ c_fin_src,
                              float* __restrict__ dst_h,
                              float* __restrict__ dst_c) {
    const int i = blockIdx.x * blockDim.x + threadIdx.x;
    if (i < BH) { dst_h[i] = h_fin_src[i]; dst_c[i] = c_fin_src[i]; }
}

// ---------------- host ----------------

extern "C" void kernel_launch(void* const* d_in, const int* in_sizes, int n_in,
                              void* d_out, int out_size, void* d_ws, size_t ws_size,
                              hipStream_t stream) {
    const float* input = (const float*)d_in[0];
    const float* h0    = (const float*)d_in[1];
    const float* c0    = (const float*)d_in[2];
    const float* W_ih  = (const float*)d_in[3];
    const float* W_hh  = (const float*)d_in[4];
    const float* b_ih  = (const float*)d_in[5];
    const float* b_hh  = (const float*)d_in[6];
    float* out = (float*)d_out;

    // ws carve-up (bytes)
    const size_t OFF_XHI   = 0;                         // 64 MiB
    const size_t OFF_XLO   = OFF_XHI + 67108864ULL;     // 64 MiB
    const size_t OFF_WPK   = OFF_XLO + 67108864ULL;     // 32 MiB
    const size_t OFF_BIAS  = OFF_WPK + 33554432ULL;     // 16 KiB
    const size_t OFF_HA    = OFF_BIAS + 16384ULL;       // 128 KiB packed hT A
    const size_t OFF_HB    = OFF_HA + 131072ULL;        // 128 KiB packed hT B
    const size_t OFF_BAR   = OFF_HB + 131072ULL;        // 16 KiB barrier
    const size_t NEED      = OFF_BAR + 16384ULL;

    if (ws_size >= NEED) {
        unsigned char* w = (unsigned char*)d_ws;
        unsigned short* x_hi = (unsigned short*)(w + OFF_XHI);
        unsigned short* x_lo = (unsigned short*)(w + OFF_XLO);
        unsigned short* Wpk  = (unsigned short*)(w + OFF_WPK);
        float*          bias = (float*)(w + OFF_BIAS);
        unsigned*       hA   = (unsigned*)(w + OFF_HA);
        unsigned*       hB   = (unsigned*)(w + OFF_HB);
        unsigned*       bar  = (unsigned*)(w + OFF_BAR);

        hipLaunchKernelGGL(convert_split, dim3(4096), dim3(256), 0, stream,
                           input, x_hi, x_lo, T_STEPS * BH / 4);
        hipLaunchKernelGGL(pack_W, dim3(8192), dim3(256), 0, stream,
                           W_ih, W_hh, Wpk);
        hipLaunchKernelGGL(prep_state, dim3(128), dim3(256), 0, stream,
                           h0, b_ih, b_hh, hA, bias, bar);

        (void)hipFuncSetAttribute(reinterpret_cast<const void*>(lstm_persistent),
                                  hipFuncAttributeMaxDynamicSharedMemorySize, 147456);
        hipLaunchKernelGGL(lstm_persistent, dim3(NBLK), dim3(512), 147456, stream,
                           x_hi, x_lo, Wpk, hA, hB, bias, c0, out, bar);
    } else {
        // fallback: round-1 path (c scratch only)
        float* c_ws = (float*)d_ws;
        for (int t = T_STEPS - 1; t >= 0; --t) {
            const float* x_t = input + (size_t)t * BATCH * IN_DIM;
            const float* hp  = (t == T_STEPS - 1) ? h0 : out + (size_t)(t + 1) * BH;
            const float* cp  = (t == T_STEPS - 1) ? c0 : c_ws;
            hipLaunchKernelGGL(lstm_step_fused, dim3(128), dim3(256), 0, stream,
                               x_t, hp, cp, c_ws, out + (size_t)t * BH,
                               W_ih, W_hh, b_ih, b_hh);
        }
        hipLaunchKernelGGL(lstm_finalize, dim3(128), dim3(256), 0, stream,
                           out, c_ws,
                           out + (size_t)T_STEPS * BH,
                           out + (size_t)T_STEPS * BH + BH);
    }
}

// Round 10
// 14023.267 us; speedup vs baseline: 1.4450x; 1.4450x over previous
//
#include <hip/hip_runtime.h>

// ReverseLSTMLayer: T=1024, B=32, I=1024, H=1024, fp32 in/out.
// d_out layout: outputs [T*B*H] | h_fin [B*H] | c_fin [B*H].
//
// Round 10 = round 9 with the barrier deadlock fixed:
//  - grid-finisher predicate is (r & 15) == 15  [rcnt gets 16 adds/step,
//    one per group finisher -- round 9's (r & 255) fired every 16th step
//    => all tid0 pollers hung].
//  - tid0 poll regains the bounded-spin RMW fallback (hang insurance).
// Everything else as round 9:
//  - monotonic 2-level barrier: group release-RMW -> root RMW ->
//    root-finisher broadcasts step# to 16 group lines -> tid0 polls own line.
//  - wave-0-only h publication: epilogue -> LDS pkbuf -> wave 0 stores 64
//    coalesced 8B agent-atomics -> tid0 release-RMW arrival.
//  - ONE acquire-fence per block per step (tid0, after poll).
//  - h layout [b][col] packed uint, uint4 consumer loads.
//  - branchless tanh/sigmoid via __expf.
// Split-bf16 3-pass MFMA numerics (proven absmax 0.0039, rounds 2-8).

constexpr int T_STEPS = 1024;
constexpr int BATCH   = 32;
constexpr int IN_DIM  = 1024;
constexpr int HID     = 1024;
constexpr int BH      = BATCH * HID;   // 32768
constexpr int NBLK    = 256;

typedef __attribute__((ext_vector_type(8))) short  short8;
typedef __attribute__((ext_vector_type(4))) float  f32x4;

__device__ __forceinline__ unsigned short f2bf(float f) {
    union { float f; unsigned u; } x; x.f = f;
    unsigned r = (x.u + 0x7fffu + ((x.u >> 16) & 1u)) >> 16;
    return (unsigned short)r;
}
__device__ __forceinline__ float bf2f(unsigned short h) {
    union { unsigned u; float f; } x; x.u = ((unsigned)h) << 16;
    return x.f;
}
__device__ __forceinline__ f32x4 mfma16(short8 a, short8 b, f32x4 c) {
    return __builtin_amdgcn_mfma_f32_16x16x32_bf16(a, b, c, 0, 0, 0);
}
__device__ __forceinline__ unsigned rmw_add_rlx(unsigned* p, unsigned v) {
    return __hip_atomic_fetch_add(p, v, __ATOMIC_RELAXED, __HIP_MEMORY_SCOPE_AGENT);
}
__device__ __forceinline__ unsigned rmw_add_rel(unsigned* p, unsigned v) {
    return __hip_atomic_fetch_add(p, v, __ATOMIC_RELEASE, __HIP_MEMORY_SCOPE_AGENT);
}
__device__ __forceinline__ unsigned flag_ld(const unsigned* p) {
    return __hip_atomic_load(p, __ATOMIC_RELAXED, __HIP_MEMORY_SCOPE_AGENT);
}
__device__ __forceinline__ float sigmoid_fast(float x) {
    return 1.0f / (1.0f + __expf(-x));
}
__device__ __forceinline__ float tanh_fast(float x) {
    const float t = __expf(-2.0f * fabsf(x));
    const float r = (1.0f - t) / (1.0f + t);
    return copysignf(r, x);
}

// ---------------- one-time converters ----------------

__global__ void convert_split(const float* __restrict__ src,
                              unsigned short* __restrict__ hi,
                              unsigned short* __restrict__ lo, int n4) {
    for (int i = blockIdx.x * blockDim.x + threadIdx.x; i < n4;
         i += gridDim.x * blockDim.x) {
        const float4 v = ((const float4*)src)[i];
        ushort4 h, l;
        float t;
        h.x = f2bf(v.x); t = v.x - bf2f(h.x); l.x = f2bf(t);
        h.y = f2bf(v.y); t = v.y - bf2f(h.y); l.y = f2bf(t);
        h.z = f2bf(v.z); t = v.z - bf2f(h.z); l.z = f2bf(t);
        h.w = f2bf(v.w); t = v.w - bf2f(h.w); l.w = f2bf(t);
        ((ushort4*)hi)[i] = h;
        ((ushort4*)lo)[i] = l;
    }
}

// Wpk[blk][half(hi=0,lo=1)][kstep 0..63][lane 0..63][8 elems].
// (blk, lane): m=lane&15, kg=(lane>>4)*8, row=(m>>2)*1024+blk*4+(m&3),
// k = kstep*32+kg; k<1024 -> W_ih, else W_hh.
__global__ void pack_W(const float* __restrict__ W_ih,
                       const float* __restrict__ W_hh,
                       unsigned short* __restrict__ Wpk) {
    const int i = blockIdx.x * blockDim.x + threadIdx.x;   // 0 .. 2,097,151
    const int lane = i & 63;
    const int s    = (i >> 6) & 63;
    const int half = (i >> 12) & 1;
    const int blk  = i >> 13;
    if (blk >= NBLK) return;
    const int m   = lane & 15;
    const int kg  = (lane >> 4) << 3;
    const int row = ((m >> 2) << 10) + (blk << 2) + (m & 3);
    const int k   = (s << 5) + kg;
    const float* src = (k < IN_DIM) ? (W_ih + (size_t)row * IN_DIM + k)
                                    : (W_hh + (size_t)row * HID + (k - IN_DIM));
    unsigned short v[8];
    #pragma unroll
    for (int e = 0; e < 8; ++e) {
        const float f = src[e];
        const unsigned short h = f2bf(f);
        v[e] = half ? f2bf(f - bf2f(h)) : h;
    }
    ushort4* dst = (ushort4*)(Wpk + (size_t)i * 8);
    dst[0] = make_ushort4(v[0], v[1], v[2], v[3]);
    dst[1] = make_ushort4(v[4], v[5], v[6], v[7]);
}

// h0 pack ([b][col], packed hi|lo), bias combine, barrier reset.
__global__ void prep_state(const float* __restrict__ h0,
                           const float* __restrict__ b_ih,
                           const float* __restrict__ b_hh,
                           unsigned* __restrict__ h_pk,
                           float* __restrict__ bias,
                           unsigned* __restrict__ bar) {
    const int i = blockIdx.x * blockDim.x + threadIdx.x;
    if (i < BH) {
        const float v = h0[i];
        const unsigned short hh = f2bf(v);
        const unsigned short hl = f2bf(v - bf2f(hh));
        h_pk[i] = ((unsigned)hh << 16) | (unsigned)hl;
    }
    if (i < 4 * HID) bias[i] = b_ih[i] + b_hh[i];
    if (i < 4096) bar[i] = 0u;
}

// ---------------- persistent LSTM scan ----------------
// Dynamic LDS: [0,128K) W; [128K,144K) reduce float[16][256];
//              [144K,144K+512) pkbuf (packed h handoff).
// bar[]: gcnt[g]=bar[g*64] (g=blk&15), gph[g]=bar[1024+g*64], rcnt=bar[2048].
// Monotonic: after step i, gcnt[g]=16(i+1), rcnt=16(i+1), gph[g]=i+1.
__global__ __launch_bounds__(512, 2) void lstm_persistent(
    const unsigned short* __restrict__ x_hi,   // [T][32][1024]
    const unsigned short* __restrict__ x_lo,
    const unsigned short* __restrict__ Wpk,    // [256][2][64][64][8]
    unsigned* __restrict__ hA_pk,              // [32][1024] packed hi|lo
    unsigned* __restrict__ hB_pk,
    const float* __restrict__ bias,            // [4096]
    const float* __restrict__ c0,              // [32][1024]
    float* __restrict__ out,
    unsigned* __restrict__ bar)
{
    extern __shared__ unsigned char smem[];
    float* red = (float*)(smem + 131072);
    unsigned* pkbuf = (unsigned*)(smem + 147456);

    const int tid  = threadIdx.x;
    const int wave = tid >> 6;
    const int lane = tid & 63;
    const int blk  = blockIdx.x;

    // One-time: copy this block's 128 KiB W slice into LDS (coalesced).
    {
        const uint4* src = (const uint4*)Wpk + (size_t)blk * 8192;
        uint4* dst = (uint4*)smem;
        #pragma unroll
        for (int r = 0; r < 16; ++r) dst[r * 512 + tid] = src[r * 512 + tid];
    }

    const int m16    = lane & 15;
    const int kg     = (lane >> 4) << 3;
    const int off_b0 = m16 * HID + (wave << 7) + kg;   // frag base, b 0-15
    const int off_b1 = off_b0 + 16 * HID;              // b 16-31
    const int wbyte  = lane << 4;

    // Per-thread persistent epilogue state (tid < 128): c + bias.
    float c_reg = 0.f;
    float bias_reg[4] = {0.f, 0.f, 0.f, 0.f};
    const int b_own   = tid >> 2;
    const int jj      = tid & 3;
    const int col_own = (blk << 2) + jj;
    const int idx_own = b_own * HID + col_own;
    if (tid < 128) {
        #pragma unroll
        for (int g = 0; g < 4; ++g) bias_reg[g] = bias[g * HID + col_own];
        c_reg = c0[idx_own];
    }

    unsigned* const gcnt   = bar + ((blk & 15) * 64);
    unsigned* const gph_my = bar + 1024 + ((blk & 15) * 64);
    unsigned* const rcnt   = bar + 2048;

    __syncthreads();

    unsigned* hin  = hA_pk;
    unsigned* hout = hB_pk;

    // Prefetch x fragments for the first step.
    short8 pxh0[4], pxh1[4], pxl0[4], pxl1[4];
    {
        const unsigned short* xh = x_hi + (size_t)(T_STEPS - 1) * BH;
        const unsigned short* xl = x_lo + (size_t)(T_STEPS - 1) * BH;
        #pragma unroll
        for (int sq = 0; sq < 4; ++sq) {
            pxh0[sq] = *(const short8*)(xh + off_b0 + (sq << 5));
            pxh1[sq] = *(const short8*)(xh + off_b1 + (sq << 5));
            pxl0[sq] = *(const short8*)(xl + off_b0 + (sq << 5));
            pxl1[sq] = *(const short8*)(xl + off_b1 + (sq << 5));
        }
    }

    for (int i = 0; i < T_STEPS; ++i) {
        const int t = T_STEPS - 1 - i;

        f32x4 acc0 = {0.f, 0.f, 0.f, 0.f};
        f32x4 acc1 = {0.f, 0.f, 0.f, 0.f};

        // x-part MFMAs (independent of h -> overlap the wait).
        #pragma unroll
        for (int sq = 0; sq < 4; ++sq) {
            const int s = (wave << 2) + sq;
            const short8 whi = *(const short8*)(smem + (size_t)s * 1024 + wbyte);
            const short8 wlo = *(const short8*)(smem + (size_t)(64 + s) * 1024 + wbyte);
            acc0 = mfma16(whi, pxh0[sq], acc0);
            acc0 = mfma16(whi, pxl0[sq], acc0);
            acc0 = mfma16(wlo, pxh0[sq], acc0);
            acc1 = mfma16(whi, pxh1[sq], acc1);
            acc1 = mfma16(whi, pxl1[sq], acc1);
            acc1 = mfma16(wlo, pxh1[sq], acc1);
        }

        // Issue next-step x prefetch (completes under the h wait/compute).
        if (i + 1 < T_STEPS) {
            const unsigned short* xh = x_hi + (size_t)(t - 1) * BH;
            const unsigned short* xl = x_lo + (size_t)(t - 1) * BH;
            #pragma unroll
            for (int sq = 0; sq < 4; ++sq) {
                pxh0[sq] = *(const short8*)(xh + off_b0 + (sq << 5));
                pxh1[sq] = *(const short8*)(xh + off_b1 + (sq << 5));
                pxl0[sq] = *(const short8*)(xl + off_b0 + (sq << 5));
                pxl1[sq] = *(const short8*)(xl + off_b1 + (sq << 5));
            }
        }

        // Wait for h(i-1): tid0 polls own group line (bounded-spin RMW
        // fallback), then one acquire-fence; __syncthreads releases others.
        if (i > 0) {
            if (tid == 0) {
                int spins = 0;
                while (flag_ld(gph_my) < (unsigned)i) {
                    __builtin_amdgcn_s_sleep(1);
                    if (++spins > 16384) {
                        if (rmw_add_rlx(gph_my, 0u) >= (unsigned)i) break;
                        spins = 8192;
                    }
                }
                __builtin_amdgcn_fence(__ATOMIC_ACQUIRE, "agent");
            }
            __syncthreads();
        }

        // h loads (uint4, cached; fresh post-invalidate, L2 dedups per XCD).
        uint4 hp0[8], hp1[8];
        #pragma unroll
        for (int sq = 0; sq < 4; ++sq) {
            const uint4* p0 = (const uint4*)(hin + off_b0 + (sq << 5));
            const uint4* p1 = (const uint4*)(hin + off_b1 + (sq << 5));
            hp0[sq * 2]     = p0[0];
            hp0[sq * 2 + 1] = p0[1];
            hp1[sq * 2]     = p1[0];
            hp1[sq * 2 + 1] = p1[1];
        }

        // h-part MFMAs.
        #pragma unroll
        for (int sq = 0; sq < 4; ++sq) {
            const int s = 32 + (wave << 2) + sq;
            const short8 whi = *(const short8*)(smem + (size_t)s * 1024 + wbyte);
            const short8 wlo = *(const short8*)(smem + (size_t)(64 + s) * 1024 + wbyte);
            short8 hh0, hl0, hh1, hl1;
            const uint4 a0v = hp0[sq * 2], b0v = hp0[sq * 2 + 1];
            const uint4 a1v = hp1[sq * 2], b1v = hp1[sq * 2 + 1];
            hh0[0]=(short)(a0v.x>>16); hl0[0]=(short)(a0v.x&0xffffu);
            hh0[1]=(short)(a0v.y>>16); hl0[1]=(short)(a0v.y&0xffffu);
            hh0[2]=(short)(a0v.z>>16); hl0[2]=(short)(a0v.z&0xffffu);
            hh0[3]=(short)(a0v.w>>16); hl0[3]=(short)(a0v.w&0xffffu);
            hh0[4]=(short)(b0v.x>>16); hl0[4]=(short)(b0v.x&0xffffu);
            hh0[5]=(short)(b0v.y>>16); hl0[5]=(short)(b0v.y&0xffffu);
            hh0[6]=(short)(b0v.z>>16); hl0[6]=(short)(b0v.z&0xffffu);
            hh0[7]=(short)(b0v.w>>16); hl0[7]=(short)(b0v.w&0xffffu);
            hh1[0]=(short)(a1v.x>>16); hl1[0]=(short)(a1v.x&0xffffu);
            hh1[1]=(short)(a1v.y>>16); hl1[1]=(short)(a1v.y&0xffffu);
            hh1[2]=(short)(a1v.z>>16); hl1[2]=(short)(a1v.z&0xffffu);
            hh1[3]=(short)(a1v.w>>16); hl1[3]=(short)(a1v.w&0xffffu);
            hh1[4]=(short)(b1v.x>>16); hl1[4]=(short)(b1v.x&0xffffu);
            hh1[5]=(short)(b1v.y>>16); hl1[5]=(short)(b1v.y&0xffffu);
            hh1[6]=(short)(b1v.z>>16); hl1[6]=(short)(b1v.z&0xffffu);
            hh1[7]=(short)(b1v.w>>16); hl1[7]=(short)(b1v.w&0xffffu);
            acc0 = mfma16(whi, hh0, acc0);
            acc0 = mfma16(whi, hl0, acc0);
            acc0 = mfma16(wlo, hh0, acc0);
            acc1 = mfma16(whi, hh1, acc1);
            acc1 = mfma16(whi, hl1, acc1);
            acc1 = mfma16(wlo, hh1, acc1);
        }

        // Cross-wave reduce. C/D layout (m89): col=lane&15, row=4*(lane>>4)+r.
        {
            const int arow = (lane >> 4) << 2;
            const int acol = lane & 15;
            #pragma unroll
            for (int r = 0; r < 4; ++r) {
                red[((wave << 1) + 0) * 256 + (arow + r) * 16 + acol] = acc0[r];
                red[((wave << 1) + 1) * 256 + (arow + r) * 16 + acol] = acc1[r];
            }
        }
        __syncthreads();

        if (tid < 128) {
            const int mt  = b_own >> 4;
            const int c16 = b_own & 15;
            float val[4];
            #pragma unroll
            for (int g = 0; g < 4; ++g) {
                const int rr = ((g << 2) + jj) * 16 + c16;
                float sacc = 0.f;
                #pragma unroll
                for (int w = 0; w < 8; ++w) sacc += red[((w << 1) + mt) * 256 + rr];
                val[g] = sacc + bias_reg[g];
            }
            const float ig = sigmoid_fast(val[0]);
            const float fg = sigmoid_fast(val[1]);
            const float gg = tanh_fast(val[2]);
            const float og = sigmoid_fast(val[3]);
            c_reg = fg * c_reg + ig * gg;
            const float h_new = og * tanh_fast(c_reg);
            out[(size_t)t * BH + idx_own] = h_new;               // plain cached
            const unsigned short hh = f2bf(h_new);
            const unsigned short hl = f2bf(h_new - bf2f(hh));
            pkbuf[tid] = ((unsigned)hh << 16) | (unsigned)hl;    // LDS handoff
            if (t == 0) out[(size_t)T_STEPS * BH + idx_own] = h_new;  // h_fin
        }
        __syncthreads();   // pkbuf visible to wave 0

        // Wave 0 publishes h: 64 coalesced 8B agent stores.
        if (tid < 64) {
            const int b    = tid >> 1;
            const int half = tid & 1;
            const unsigned long long v =
                *(const unsigned long long*)&pkbuf[(b << 2) + (half << 1)];
            __hip_atomic_store(
                (unsigned long long*)(hout + b * HID + (blk << 2)) + half, v,
                __ATOMIC_RELAXED, __HIP_MEMORY_SCOPE_AGENT);
        }
        // Arrival: release-RMW drains wave0's h stores; 2-level monotonic.
        if (tid == 0) {
            const unsigned a = rmw_add_rel(gcnt, 1u);
            if ((a & 15u) == 15u) {               // group finisher
                const unsigned r = rmw_add_rlx(rcnt, 1u);
                if ((r & 15u) == 15u) {           // grid finisher: broadcast
                    #pragma unroll
                    for (int g = 0; g < 16; ++g)
                        __hip_atomic_store(bar + 1024 + g * 64, (unsigned)(i + 1),
                                           __ATOMIC_RELAXED,
                                           __HIP_MEMORY_SCOPE_AGENT);
                }
            }
        }
        // No trailing block sync: waves 1-7 run ahead to next x-MFMAs and
        // wait at the post-poll __syncthreads.

        unsigned* th = hin; hin = hout; hout = th;
    }

    if (tid < 128)
        out[(size_t)T_STEPS * BH + BH + idx_own] = c_reg;   // c_fin
}

// ---------------- fallback (round-1, known-good, slow) ----------------
__global__ __launch_bounds__(256) void lstm_step_fused(
    const float* __restrict__ x_t, const float* __restrict__ h_prev,
    const float* __restrict__ c_prev, float* __restrict__ c_out,
    float* __restrict__ h_out, const float* __restrict__ W_ih,
    const float* __restrict__ W_hh, const float* __restrict__ b_ih,
    const float* __restrict__ b_hh) {
    __shared__ float xs[IN_DIM];
    __shared__ float hs[HID];
    const int tid = threadIdx.x;
    const int b   = blockIdx.x >> 2;
    const int j   = ((blockIdx.x & 3) << 8) | tid;
    ((float4*)xs)[tid] = ((const float4*)(x_t    + (size_t)b * IN_DIM))[tid];
    ((float4*)hs)[tid] = ((const float4*)(h_prev + (size_t)b * HID))[tid];
    __syncthreads();
    float a0 = b_ih[j] + b_hh[j];
    float a1 = b_ih[HID + j] + b_hh[HID + j];
    float a2 = b_ih[2*HID + j] + b_hh[2*HID + j];
    float a3 = b_ih[3*HID + j] + b_hh[3*HID + j];
    {
        const float4* wi0 = (const float4*)(W_ih + (size_t)(0*HID + j) * IN_DIM);
        const float4* wi1 = (const float4*)(W_ih + (size_t)(1*HID + j) * IN_DIM);
        const float4* wi2 = (const float4*)(W_ih + (size_t)(2*HID + j) * IN_DIM);
        const float4* wi3 = (const float4*)(W_ih + (size_t)(3*HID + j) * IN_DIM);
        const float4* xs4 = (const float4*)xs;
        #pragma unroll 4
        for (int k = 0; k < IN_DIM / 4; ++k) {
            const float4 xv = xs4[k]; float4 w;
            w = wi0[k]; a0 += xv.x*w.x + xv.y*w.y + xv.z*w.z + xv.w*w.w;
            w = wi1[k]; a1 += xv.x*w.x + xv.y*w.y + xv.z*w.z + xv.w*w.w;
            w = wi2[k]; a2 += xv.x*w.x + xv.y*w.y + xv.z*w.z + xv.w*w.w;
            w = wi3[k]; a3 += xv.x*w.x + xv.y*w.y + xv.z*w.z + xv.w*w.w;
        }
    }
    {
        const float4* wh0 = (const float4*)(W_hh + (size_t)(0*HID + j) * HID);
        const float4* wh1 = (const float4*)(W_hh + (size_t)(1*HID + j) * HID);
        const float4* wh2 = (const float4*)(W_hh + (size_t)(2*HID + j) * HID);
        const float4* wh3 = (const float4*)(W_hh + (size_t)(3*HID + j) * HID);
        const float4* hs4 = (const float4*)hs;
        #pragma unroll 4
        for (int k = 0; k < HID / 4; ++k) {
            const float4 hv = hs4[k]; float4 w;
            w = wh0[k]; a0 += hv.x*w.x + hv.y*w.y + hv.z*w.z + hv.w*w.w;
            w = wh1[k]; a1 += hv.x*w.x + hv.y*w.y + hv.z*w.z + hv.w*w.w;
            w = wh2[k]; a2 += hv.x*w.x + hv.y*w.y + hv.z*w.z + hv.w*w.w;
            w = wh3[k]; a3 += hv.x*w.x + hv.y*w.y + hv.z*w.z + hv.w*w.w;
        }
    }
    const float ig = 1.0f / (1.0f + __expf(-a0));
    const float fg = 1.0f / (1.0f + __expf(-a1));
    const float gg = tanhf(a2);
    const float og = 1.0f / (1.0f + __expf(-a3));
    const size_t idx = (size_t)b * HID + j;
    const float c_new = fg * c_prev[idx] + ig * gg;
    c_out[idx] = c_new;
    h_out[idx] = og * tanhf(c_new);
}

__global__ void lstm_finalize(const float* __restrict__ h_fin_src,
                              const float* __restrict__ c_fin_src,
                              float* __restrict__ dst_h,
                              float* __restrict__ dst_c) {
    const int i = blockIdx.x * blockDim.x + threadIdx.x;
    if (i < BH) { dst_h[i] = h_fin_src[i]; dst_c[i] = c_fin_src[i]; }
}

// ---------------- host ----------------

extern "C" void kernel_launch(void* const* d_in, const int* in_sizes, int n_in,
                              void* d_out, int out_size, void* d_ws, size_t ws_size,
                              hipStream_t stream) {
    const float* input = (const float*)d_in[0];
    const float* h0    = (const float*)d_in[1];
    const float* c0    = (const float*)d_in[2];
    const float* W_ih  = (const float*)d_in[3];
    const float* W_hh  = (const float*)d_in[4];
    const float* b_ih  = (const float*)d_in[5];
    const float* b_hh  = (const float*)d_in[6];
    float* out = (float*)d_out;

    // ws carve-up (bytes)
    const size_t OFF_XHI   = 0;                         // 64 MiB
    const size_t OFF_XLO   = OFF_XHI + 67108864ULL;     // 64 MiB
    const size_t OFF_WPK   = OFF_XLO + 67108864ULL;     // 32 MiB
    const size_t OFF_BIAS  = OFF_WPK + 33554432ULL;     // 16 KiB
    const size_t OFF_HA    = OFF_BIAS + 16384ULL;       // 128 KiB packed h A
    const size_t OFF_HB    = OFF_HA + 131072ULL;        // 128 KiB packed h B
    const size_t OFF_BAR   = OFF_HB + 131072ULL;        // 16 KiB barrier
    const size_t NEED      = OFF_BAR + 16384ULL;

    if (ws_size >= NEED) {
        unsigned char* w = (unsigned char*)d_ws;
        unsigned short* x_hi  = (unsigned short*)(w + OFF_XHI);
        unsigned short* x_lo  = (unsigned short*)(w + OFF_XLO);
        unsigned short* Wpk   = (unsigned short*)(w + OFF_WPK);
        float*          bias  = (float*)(w + OFF_BIAS);
        unsigned*       hA_pk = (unsigned*)(w + OFF_HA);
        unsigned*       hB_pk = (unsigned*)(w + OFF_HB);
        unsigned*       bar   = (unsigned*)(w + OFF_BAR);

        hipLaunchKernelGGL(convert_split, dim3(4096), dim3(256), 0, stream,
                           input, x_hi, x_lo, T_STEPS * BH / 4);
        hipLaunchKernelGGL(pack_W, dim3(8192), dim3(256), 0, stream,
                           W_ih, W_hh, Wpk);
        hipLaunchKernelGGL(prep_state, dim3(128), dim3(256), 0, stream,
                           h0, b_ih, b_hh, hA_pk, bias, bar);

        (void)hipFuncSetAttribute(reinterpret_cast<const void*>(lstm_persistent),
                                  hipFuncAttributeMaxDynamicSharedMemorySize, 147968);
        hipLaunchKernelGGL(lstm_persistent, dim3(NBLK), dim3(512), 147968, stream,
                           x_hi, x_lo, Wpk, hA_pk, hB_pk, bias, c0, out, bar);
    } else {
        // fallback: round-1 path (c scratch only)
        float* c_ws = (float*)d_ws;
        for (int t = T_STEPS - 1; t >= 0; --t) {
            const float* x_t = input + (size_t)t * BATCH * IN_DIM;
            const float* hp  = (t == T_STEPS - 1) ? h0 : out + (size_t)(t + 1) * BH;
            const float* cp  = (t == T_STEPS - 1) ? c0 : c_ws;
            hipLaunchKernelGGL(lstm_step_fused, dim3(128), dim3(256), 0, stream,
                               x_t, hp, cp, c_ws, out + (size_t)t * BH,
                               W_ih, W_hh, b_ih, b_hh);
        }
        hipLaunchKernelGGL(lstm_finalize, dim3(128), dim3(256), 0, stream,
                           out, c_ws,
                           out + (size_t)T_STEPS * BH,
                           out + (size_t)T_STEPS * BH + BH);
    }
}

// Round 11
// 12603.663 us; speedup vs baseline: 1.6077x; 1.1126x over previous
//
#include <hip/hip_runtime.h>

// ReverseLSTMLayer: T=1024, B=32, I=1024, H=1024, fp32 in/out.
// d_out layout: outputs [T*B*H] | h_fin [B*H] | c_fin [B*H].
//
// Round 11: forward/backward sync decoupled.
//  FORWARD (critical path): producer h stores (relaxed agent atomics, CP) ->
//    __syncthreads drains -> tid0 stores pdone[blk]=i+1 -> consumer wave w
//    polls its 32 producers' flags (lanes 0-31, __all) -> CP-atomic u64 h
//    loads (round-6 proven; always fresh, NO acquire fence anywhere).
//  BACKWARD (slack path): 3-slot h ring; consumption tracked by the r10
//    monotonic tree barrier (all-relaxed RMWs + root broadcast, fixed
//    (r&15) arithmetic), arrived after h-MFMAs; producers check it one-plus
//    steps late (gph >= i-1) -- pre-satisfied, off the critical path.
//  x/W caching: never invalidated (no fences in the loop at all).
// Split-bf16 3-pass MFMA numerics (proven absmax 0.0039, rounds 2-10).

constexpr int T_STEPS = 1024;
constexpr int BATCH   = 32;
constexpr int IN_DIM  = 1024;
constexpr int HID     = 1024;
constexpr int BH      = BATCH * HID;   // 32768
constexpr int NBLK    = 256;

typedef __attribute__((ext_vector_type(8))) short  short8;
typedef __attribute__((ext_vector_type(4))) float  f32x4;

__device__ __forceinline__ unsigned short f2bf(float f) {
    union { float f; unsigned u; } x; x.f = f;
    unsigned r = (x.u + 0x7fffu + ((x.u >> 16) & 1u)) >> 16;
    return (unsigned short)r;
}
__device__ __forceinline__ float bf2f(unsigned short h) {
    union { unsigned u; float f; } x; x.u = ((unsigned)h) << 16;
    return x.f;
}
__device__ __forceinline__ f32x4 mfma16(short8 a, short8 b, f32x4 c) {
    return __builtin_amdgcn_mfma_f32_16x16x32_bf16(a, b, c, 0, 0, 0);
}
__device__ __forceinline__ unsigned rmw_add_rlx(unsigned* p, unsigned v) {
    return __hip_atomic_fetch_add(p, v, __ATOMIC_RELAXED, __HIP_MEMORY_SCOPE_AGENT);
}
__device__ __forceinline__ unsigned flag_ld(const unsigned* p) {
    return __hip_atomic_load(p, __ATOMIC_RELAXED, __HIP_MEMORY_SCOPE_AGENT);
}
__device__ __forceinline__ float sigmoid_fast(float x) {
    return 1.0f / (1.0f + __expf(-x));
}
__device__ __forceinline__ float tanh_fast(float x) {
    const float t = __expf(-2.0f * fabsf(x));
    const float r = (1.0f - t) / (1.0f + t);
    return copysignf(r, x);
}

// Load 8 packed-h uints (4 u64 CP-atomic loads) -> bf16 hi/lo fragments.
__device__ __forceinline__ void unpack8(const unsigned long long* p,
                                        short8& hi, short8& lo) {
    const unsigned long long u0 = __hip_atomic_load(p + 0, __ATOMIC_RELAXED, __HIP_MEMORY_SCOPE_AGENT);
    const unsigned long long u1 = __hip_atomic_load(p + 1, __ATOMIC_RELAXED, __HIP_MEMORY_SCOPE_AGENT);
    const unsigned long long u2 = __hip_atomic_load(p + 2, __ATOMIC_RELAXED, __HIP_MEMORY_SCOPE_AGENT);
    const unsigned long long u3 = __hip_atomic_load(p + 3, __ATOMIC_RELAXED, __HIP_MEMORY_SCOPE_AGENT);
    unsigned a;
    a = (unsigned)u0;         hi[0] = (short)(a >> 16); lo[0] = (short)(a & 0xffffu);
    a = (unsigned)(u0 >> 32); hi[1] = (short)(a >> 16); lo[1] = (short)(a & 0xffffu);
    a = (unsigned)u1;         hi[2] = (short)(a >> 16); lo[2] = (short)(a & 0xffffu);
    a = (unsigned)(u1 >> 32); hi[3] = (short)(a >> 16); lo[3] = (short)(a & 0xffffu);
    a = (unsigned)u2;         hi[4] = (short)(a >> 16); lo[4] = (short)(a & 0xffffu);
    a = (unsigned)(u2 >> 32); hi[5] = (short)(a >> 16); lo[5] = (short)(a & 0xffffu);
    a = (unsigned)u3;         hi[6] = (short)(a >> 16); lo[6] = (short)(a & 0xffffu);
    a = (unsigned)(u3 >> 32); hi[7] = (short)(a >> 16); lo[7] = (short)(a & 0xffffu);
}

// ---------------- one-time converters ----------------

__global__ void convert_split(const float* __restrict__ src,
                              unsigned short* __restrict__ hi,
                              unsigned short* __restrict__ lo, int n4) {
    for (int i = blockIdx.x * blockDim.x + threadIdx.x; i < n4;
         i += gridDim.x * blockDim.x) {
        const float4 v = ((const float4*)src)[i];
        ushort4 h, l;
        float t;
        h.x = f2bf(v.x); t = v.x - bf2f(h.x); l.x = f2bf(t);
        h.y = f2bf(v.y); t = v.y - bf2f(h.y); l.y = f2bf(t);
        h.z = f2bf(v.z); t = v.z - bf2f(h.z); l.z = f2bf(t);
        h.w = f2bf(v.w); t = v.w - bf2f(h.w); l.w = f2bf(t);
        ((ushort4*)hi)[i] = h;
        ((ushort4*)lo)[i] = l;
    }
}

// Wpk[blk][half(hi=0,lo=1)][kstep 0..63][lane 0..63][8 elems].
__global__ void pack_W(const float* __restrict__ W_ih,
                       const float* __restrict__ W_hh,
                       unsigned short* __restrict__ Wpk) {
    const int i = blockIdx.x * blockDim.x + threadIdx.x;   // 0 .. 2,097,151
    const int lane = i & 63;
    const int s    = (i >> 6) & 63;
    const int half = (i >> 12) & 1;
    const int blk  = i >> 13;
    if (blk >= NBLK) return;
    const int m   = lane & 15;
    const int kg  = (lane >> 4) << 3;
    const int row = ((m >> 2) << 10) + (blk << 2) + (m & 3);
    const int k   = (s << 5) + kg;
    const float* src = (k < IN_DIM) ? (W_ih + (size_t)row * IN_DIM + k)
                                    : (W_hh + (size_t)row * HID + (k - IN_DIM));
    unsigned short v[8];
    #pragma unroll
    for (int e = 0; e < 8; ++e) {
        const float f = src[e];
        const unsigned short h = f2bf(f);
        v[e] = half ? f2bf(f - bf2f(h)) : h;
    }
    ushort4* dst = (ushort4*)(Wpk + (size_t)i * 8);
    dst[0] = make_ushort4(v[0], v[1], v[2], v[3]);
    dst[1] = make_ushort4(v[4], v[5], v[6], v[7]);
}

// h0 pack into SLOT 2 of the ring; bias combine; pdone + bar reset.
__global__ void prep_state(const float* __restrict__ h0,
                           const float* __restrict__ b_ih,
                           const float* __restrict__ b_hh,
                           unsigned* __restrict__ h_slot2,
                           float* __restrict__ bias,
                           unsigned* __restrict__ pdone,
                           unsigned* __restrict__ bar) {
    const int i = blockIdx.x * blockDim.x + threadIdx.x;
    if (i < BH) {
        const float v = h0[i];
        const unsigned short hh = f2bf(v);
        const unsigned short hl = f2bf(v - bf2f(hh));
        h_slot2[i] = ((unsigned)hh << 16) | (unsigned)hl;
    }
    if (i < 4 * HID) bias[i] = b_ih[i] + b_hh[i];
    if (i < 1024) pdone[i] = 0u;
    if (i < 4096) bar[i] = 0u;
}

// ---------------- persistent LSTM scan ----------------
// Dynamic LDS: [0,128K) W; [128K,144K) reduce float[16][256].
// pdone[blk*4] (16B padded): monotonic publish count of block blk.
// bar[]: gcnt[g]=bar[g*64] (g=blk&15), gph[g]=bar[1024+g*64], rcnt=bar[2048]
//   -- consumption barrier only (backward edge).
__global__ __launch_bounds__(512, 2) void lstm_persistent(
    const unsigned short* __restrict__ x_hi,   // [T][32][1024]
    const unsigned short* __restrict__ x_lo,
    const unsigned short* __restrict__ Wpk,    // [256][2][64][64][8]
    unsigned* __restrict__ hring,              // 3 slots x [32][1024] packed
    const float* __restrict__ bias,            // [4096]
    const float* __restrict__ c0,              // [32][1024]
    float* __restrict__ out,
    unsigned* __restrict__ pdone,
    unsigned* __restrict__ bar)
{
    extern __shared__ unsigned char smem[];
    float* red = (float*)(smem + 131072);

    const int tid  = threadIdx.x;
    const int wave = tid >> 6;
    const int lane = tid & 63;
    const int blk  = blockIdx.x;

    // One-time: copy this block's 128 KiB W slice into LDS (coalesced).
    {
        const uint4* src = (const uint4*)Wpk + (size_t)blk * 8192;
        uint4* dst = (uint4*)smem;
        #pragma unroll
        for (int r = 0; r < 16; ++r) dst[r * 512 + tid] = src[r * 512 + tid];
    }

    const int m16    = lane & 15;
    const int kg     = (lane >> 4) << 3;
    const int off_b0 = m16 * HID + (wave << 7) + kg;   // frag base, b 0-15
    const int off_b1 = off_b0 + 16 * HID;              // b 16-31
    const int wbyte  = lane << 4;

    // Per-thread persistent epilogue state (tid < 128): c + bias.
    float c_reg = 0.f;
    float bias_reg[4] = {0.f, 0.f, 0.f, 0.f};
    const int b_own   = tid >> 2;
    const int jj      = tid & 3;
    const int col_own = (blk << 2) + jj;
    const int idx_own = b_own * HID + col_own;
    if (tid < 128) {
        #pragma unroll
        for (int g = 0; g < 4; ++g) bias_reg[g] = bias[g * HID + col_own];
        c_reg = c0[idx_own];
    }

    unsigned* const gcnt   = bar + ((blk & 15) * 64);
    unsigned* const gph_my = bar + 1024 + ((blk & 15) * 64);
    unsigned* const rcnt   = bar + 2048;
    // This wave's 32 producer flags: blocks wave*32 .. wave*32+31.
    const unsigned* const my_pf = pdone + (((wave << 5) + (lane & 31)) << 2);

    __syncthreads();

    // Prefetch x fragments for the first step.
    short8 pxh0[4], pxh1[4], pxl0[4], pxl1[4];
    {
        const unsigned short* xh = x_hi + (size_t)(T_STEPS - 1) * BH;
        const unsigned short* xl = x_lo + (size_t)(T_STEPS - 1) * BH;
        #pragma unroll
        for (int sq = 0; sq < 4; ++sq) {
            pxh0[sq] = *(const short8*)(xh + off_b0 + (sq << 5));
            pxh1[sq] = *(const short8*)(xh + off_b1 + (sq << 5));
            pxl0[sq] = *(const short8*)(xl + off_b0 + (sq << 5));
            pxl1[sq] = *(const short8*)(xl + off_b1 + (sq << 5));
        }
    }

    int wslot = 0, rslot = 2;   // step i writes slot i%3, reads (i+2)%3

    for (int i = 0; i < T_STEPS; ++i) {
        const int t = T_STEPS - 1 - i;
        unsigned* const hin  = hring + (size_t)rslot * BH;
        unsigned* const hout = hring + (size_t)wslot * BH;

        f32x4 acc0 = {0.f, 0.f, 0.f, 0.f};
        f32x4 acc1 = {0.f, 0.f, 0.f, 0.f};

        // x-part MFMAs (independent of h -> overlap the producer wait).
        #pragma unroll
        for (int sq = 0; sq < 4; ++sq) {
            const int s = (wave << 2) + sq;
            const short8 whi = *(const short8*)(smem + (size_t)s * 1024 + wbyte);
            const short8 wlo = *(const short8*)(smem + (size_t)(64 + s) * 1024 + wbyte);
            acc0 = mfma16(whi, pxh0[sq], acc0);
            acc0 = mfma16(whi, pxl0[sq], acc0);
            acc0 = mfma16(wlo, pxh0[sq], acc0);
            acc1 = mfma16(whi, pxh1[sq], acc1);
            acc1 = mfma16(whi, pxl1[sq], acc1);
            acc1 = mfma16(wlo, pxh1[sq], acc1);
        }

        // Issue next-step x prefetch (completes under wait/compute).
        if (i + 1 < T_STEPS) {
            const unsigned short* xh = x_hi + (size_t)(t - 1) * BH;
            const unsigned short* xl = x_lo + (size_t)(t - 1) * BH;
            #pragma unroll
            for (int sq = 0; sq < 4; ++sq) {
                pxh0[sq] = *(const short8*)(xh + off_b0 + (sq << 5));
                pxh1[sq] = *(const short8*)(xh + off_b1 + (sq << 5));
                pxl0[sq] = *(const short8*)(xl + off_b0 + (sq << 5));
                pxl1[sq] = *(const short8*)(xl + off_b1 + (sq << 5));
            }
        }

        // FORWARD WAIT: this wave's 32 producers published step i-1?
        // Lanes 0-31 poll 32 flags in parallel; __all detects.
        if (i > 0) {
            int spins = 0;
            while (!__all(flag_ld(my_pf) >= (unsigned)i)) {
                __builtin_amdgcn_s_sleep(1);
                if (++spins > (1 << 22)) break;   // break -> absmax fail, not hang
            }
            asm volatile("" ::: "memory");        // no hoisting h loads above
        }

        // h-part: CP-atomic loads (always fresh), unpack, MFMA.
        #pragma unroll
        for (int sq = 0; sq < 4; ++sq) {
            const int s = 32 + (wave << 2) + sq;
            const short8 whi = *(const short8*)(smem + (size_t)s * 1024 + wbyte);
            const short8 wlo = *(const short8*)(smem + (size_t)(64 + s) * 1024 + wbyte);
            short8 hh0, hl0, hh1, hl1;
            unpack8((const unsigned long long*)(hin + off_b0 + (sq << 5)), hh0, hl0);
            unpack8((const unsigned long long*)(hin + off_b1 + (sq << 5)), hh1, hl1);
            acc0 = mfma16(whi, hh0, acc0);
            acc0 = mfma16(whi, hl0, acc0);
            acc0 = mfma16(wlo, hh0, acc0);
            acc1 = mfma16(whi, hh1, acc1);
            acc1 = mfma16(whi, hl1, acc1);
            acc1 = mfma16(wlo, hh1, acc1);
        }

        // Cross-wave reduce. C/D layout (m89): col=lane&15, row=4*(lane>>4)+r.
        {
            const int arow = (lane >> 4) << 2;
            const int acol = lane & 15;
            #pragma unroll
            for (int r = 0; r < 4; ++r) {
                red[((wave << 1) + 0) * 256 + (arow + r) * 16 + acol] = acc0[r];
                red[((wave << 1) + 1) * 256 + (arow + r) * 16 + acol] = acc1[r];
            }
        }
        __syncthreads();   // (A) all h-MFMAs done; red[] ready

        // Consumption arrival (backward edge): monotonic tree + broadcast.
        if (tid == 0) {
            const unsigned a = rmw_add_rlx(gcnt, 1u);
            if ((a & 15u) == 15u) {               // group finisher
                const unsigned r = rmw_add_rlx(rcnt, 1u);
                if ((r & 15u) == 15u) {           // grid finisher: broadcast
                    #pragma unroll
                    for (int g = 0; g < 16; ++g)
                        __hip_atomic_store(bar + 1024 + g * 64, (unsigned)(i + 1),
                                           __ATOMIC_RELAXED,
                                           __HIP_MEMORY_SCOPE_AGENT);
                }
            }
        }

        if (tid < 128) {
            const int mt  = b_own >> 4;
            const int c16 = b_own & 15;
            float val[4];
            #pragma unroll
            for (int g = 0; g < 4; ++g) {
                const int rr = ((g << 2) + jj) * 16 + c16;
                float sacc = 0.f;
                #pragma unroll
                for (int w = 0; w < 8; ++w) sacc += red[((w << 1) + mt) * 256 + rr];
                val[g] = sacc + bias_reg[g];
            }
            const float ig = sigmoid_fast(val[0]);
            const float fg = sigmoid_fast(val[1]);
            const float gg = tanh_fast(val[2]);
            const float og = sigmoid_fast(val[3]);
            c_reg = fg * c_reg + ig * gg;
            const float h_new = og * tanh_fast(c_reg);
            out[(size_t)t * BH + idx_own] = h_new;               // plain cached
            if (t == 0) out[(size_t)T_STEPS * BH + idx_own] = h_new;  // h_fin

            // BACKWARD CHECK (pre-satisfied; ~1.5 step slack): slot wslot was
            // read at step i-2 -> need cons(i-2) done: gph >= i-1.
            if (i >= 2) {
                int spins = 0;
                while (flag_ld(gph_my) < (unsigned)(i - 1)) {
                    __builtin_amdgcn_s_sleep(1);
                    if (++spins > 16384) {
                        if (rmw_add_rlx(gph_my, 0u) >= (unsigned)(i - 1)) break;
                        spins = 8192;
                    }
                }
            }
            const unsigned short hh = f2bf(h_new);
            const unsigned short hl = f2bf(h_new - bf2f(hh));
            __hip_atomic_store(hout + idx_own,
                               ((unsigned)hh << 16) | (unsigned)hl,
                               __ATOMIC_RELAXED, __HIP_MEMORY_SCOPE_AGENT);
        }
        __syncthreads();   // (C) drain all h stores (vmcnt=0 before s_barrier)

        // Publish: this block's h slice for step i is at the CP.
        if (tid == 0)
            __hip_atomic_store(pdone + (blk << 2), (unsigned)(i + 1),
                               __ATOMIC_RELAXED, __HIP_MEMORY_SCOPE_AGENT);

        wslot = (wslot == 2) ? 0 : wslot + 1;
        rslot = (rslot == 2) ? 0 : rslot + 1;
    }

    if (tid < 128)
        out[(size_t)T_STEPS * BH + BH + idx_own] = c_reg;   // c_fin
}

// ---------------- fallback (round-1, known-good, slow) ----------------
__global__ __launch_bounds__(256) void lstm_step_fused(
    const float* __restrict__ x_t, const float* __restrict__ h_prev,
    const float* __restrict__ c_prev, float* __restrict__ c_out,
    float* __restrict__ h_out, const float* __restrict__ W_ih,
    const float* __restrict__ W_hh, const float* __restrict__ b_ih,
    const float* __restrict__ b_hh) {
    __shared__ float xs[IN_DIM];
    __shared__ float hs[HID];
    const int tid = threadIdx.x;
    const int b   = blockIdx.x >> 2;
    const int j   = ((blockIdx.x & 3) << 8) | tid;
    ((float4*)xs)[tid] = ((const float4*)(x_t    + (size_t)b * IN_DIM))[tid];
    ((float4*)hs)[tid] = ((const float4*)(h_prev + (size_t)b * HID))[tid];
    __syncthreads();
    float a0 = b_ih[j] + b_hh[j];
    float a1 = b_ih[HID + j] + b_hh[HID + j];
    float a2 = b_ih[2*HID + j] + b_hh[2*HID + j];
    float a3 = b_ih[3*HID + j] + b_hh[3*HID + j];
    {
        const float4* wi0 = (const float4*)(W_ih + (size_t)(0*HID + j) * IN_DIM);
        const float4* wi1 = (const float4*)(W_ih + (size_t)(1*HID + j) * IN_DIM);
        const float4* wi2 = (const float4*)(W_ih + (size_t)(2*HID + j) * IN_DIM);
        const float4* wi3 = (const float4*)(W_ih + (size_t)(3*HID + j) * IN_DIM);
        const float4* xs4 = (const float4*)xs;
        #pragma unroll 4
        for (int k = 0; k < IN_DIM / 4; ++k) {
            const float4 xv = xs4[k]; float4 w;
            w = wi0[k]; a0 += xv.x*w.x + xv.y*w.y + xv.z*w.z + xv.w*w.w;
            w = wi1[k]; a1 += xv.x*w.x + xv.y*w.y + xv.z*w.z + xv.w*w.w;
            w = wi2[k]; a2 += xv.x*w.x + xv.y*w.y + xv.z*w.z + xv.w*w.w;
            w = wi3[k]; a3 += xv.x*w.x + xv.y*w.y + xv.z*w.z + xv.w*w.w;
        }
    }
    {
        const float4* wh0 = (const float4*)(W_hh + (size_t)(0*HID + j) * HID);
        const float4* wh1 = (const float4*)(W_hh + (size_t)(1*HID + j) * HID);
        const float4* wh2 = (const float4*)(W_hh + (size_t)(2*HID + j) * HID);
        const float4* wh3 = (const float4*)(W_hh + (size_t)(3*HID + j) * HID);
        const float4* hs4 = (const float4*)hs;
        #pragma unroll 4
        for (int k = 0; k < HID / 4; ++k) {
            const float4 hv = hs4[k]; float4 w;
            w = wh0[k]; a0 += hv.x*w.x + hv.y*w.y + hv.z*w.z + hv.w*w.w;
            w = wh1[k]; a1 += hv.x*w.x + hv.y*w.y + hv.z*w.z + hv.w*w.w;
            w = wh2[k]; a2 += hv.x*w.x + hv.y*w.y + hv.z*w.z + hv.w*w.w;
            w = wh3[k]; a3 += hv.x*w.x + hv.y*w.y + hv.z*w.z + hv.w*w.w;
        }
    }
    const float ig = 1.0f / (1.0f + __expf(-a0));
    const float fg = 1.0f / (1.0f + __expf(-a1));
    const float gg = tanhf(a2);
    const float og = 1.0f / (1.0f + __expf(-a3));
    const size_t idx = (size_t)b * HID + j;
    const float c_new = fg * c_prev[idx] + ig * gg;
    c_out[idx] = c_new;
    h_out[idx] = og * tanhf(c_new);
}

__global__ void lstm_finalize(const float* __restrict__ h_fin_src,
                              const float* __restrict__ c_fin_src,
                              float* __restrict__ dst_h,
                              float* __restrict__ dst_c) {
    const int i = blockIdx.x * blockDim.x + threadIdx.x;
    if (i < BH) { dst_h[i] = h_fin_src[i]; dst_c[i] = c_fin_src[i]; }
}

// ---------------- host ----------------

extern "C" void kernel_launch(void* const* d_in, const int* in_sizes, int n_in,
                              void* d_out, int out_size, void* d_ws, size_t ws_size,
                              hipStream_t stream) {
    const float* input = (const float*)d_in[0];
    const float* h0    = (const float*)d_in[1];
    const float* c0    = (const float*)d_in[2];
    const float* W_ih  = (const float*)d_in[3];
    const float* W_hh  = (const float*)d_in[4];
    const float* b_ih  = (const float*)d_in[5];
    const float* b_hh  = (const float*)d_in[6];
    float* out = (float*)d_out;

    // ws carve-up (bytes)
    const size_t OFF_XHI   = 0;                         // 64 MiB
    const size_t OFF_XLO   = OFF_XHI + 67108864ULL;     // 64 MiB
    const size_t OFF_WPK   = OFF_XLO + 67108864ULL;     // 32 MiB
    const size_t OFF_BIAS  = OFF_WPK + 33554432ULL;     // 16 KiB
    const size_t OFF_HR    = OFF_BIAS + 16384ULL;       // 3 x 128 KiB h ring
    const size_t OFF_PD    = OFF_HR + 3 * 131072ULL;    // 4 KiB pdone
    const size_t OFF_BAR   = OFF_PD + 4096ULL;          // 16 KiB barrier
    const size_t NEED      = OFF_BAR + 16384ULL;

    if (ws_size >= NEED) {
        unsigned char* w = (unsigned char*)d_ws;
        unsigned short* x_hi  = (unsigned short*)(w + OFF_XHI);
        unsigned short* x_lo  = (unsigned short*)(w + OFF_XLO);
        unsigned short* Wpk   = (unsigned short*)(w + OFF_WPK);
        float*          bias  = (float*)(w + OFF_BIAS);
        unsigned*       hring = (unsigned*)(w + OFF_HR);
        unsigned*       pdone = (unsigned*)(w + OFF_PD);
        unsigned*       bar   = (unsigned*)(w + OFF_BAR);

        hipLaunchKernelGGL(convert_split, dim3(4096), dim3(256), 0, stream,
                           input, x_hi, x_lo, T_STEPS * BH / 4);
        hipLaunchKernelGGL(pack_W, dim3(8192), dim3(256), 0, stream,
                           W_ih, W_hh, Wpk);
        hipLaunchKernelGGL(prep_state, dim3(128), dim3(256), 0, stream,
                           h0, b_ih, b_hh, hring + 2 * (size_t)BH, bias,
                           pdone, bar);

        (void)hipFuncSetAttribute(reinterpret_cast<const void*>(lstm_persistent),
                                  hipFuncAttributeMaxDynamicSharedMemorySize, 147456);
        hipLaunchKernelGGL(lstm_persistent, dim3(NBLK), dim3(512), 147456, stream,
                           x_hi, x_lo, Wpk, hring, bias, c0, out, pdone, bar);
    } else {
        // fallback: round-1 path (c scratch only)
        float* c_ws = (float*)d_ws;
        for (int t = T_STEPS - 1; t >= 0; --t) {
            const float* x_t = input + (size_t)t * BATCH * IN_DIM;
            const float* hp  = (t == T_STEPS - 1) ? h0 : out + (size_t)(t + 1) * BH;
            const float* cp  = (t == T_STEPS - 1) ? c0 : c_ws;
            hipLaunchKernelGGL(lstm_step_fused, dim3(128), dim3(256), 0, stream,
                               x_t, hp, cp, c_ws, out + (size_t)t * BH,
                               W_ih, W_hh, b_ih, b_hh);
        }
        hipLaunchKernelGGL(lstm_finalize, dim3(128), dim3(256), 0, stream,
                           out, c_ws,
                           out + (size_t)T_STEPS * BH,
                           out + (size_t)T_STEPS * BH + BH);
    }
}

// Round 12
// 9338.212 us; speedup vs baseline: 2.1699x; 1.3497x over previous
//
#include <hip/hip_runtime.h>

// ReverseLSTMLayer: T=1024, B=32, I=1024, H=1024, fp32 in/out.
// d_out layout: outputs [T*B*H] | h_fin [B*H] | c_fin [B*H].
//
// Round 12 = round 11 with ONE change (A/B on CP transaction width):
//  h reads switch from 32x u64 __hip_atomic_load per lane to 16x
//  global_load_dwordx4 sc0 sc1 (inline asm; same agent-coherence bits the
//  compiler emits for agent-scope atomics, 2x wider) issued back-to-back,
//  then s_waitcnt vmcnt(0) + sched_barrier(0) (rule #18), then unpack+MFMA.
//  CP transactions/step: 4.2M -> 2.1M. Tests the "CP transaction-rate
//  floor" hypothesis for the 12-14 us/step plateau of rounds 6-11.
// Everything else identical to round 11 (forward pdone flags, 3-slot ring,
// backward tree barrier off critical path, no fences, x/W cached).
// Split-bf16 3-pass MFMA numerics (proven absmax 0.0039, rounds 2-11).

constexpr int T_STEPS = 1024;
constexpr int BATCH   = 32;
constexpr int IN_DIM  = 1024;
constexpr int HID     = 1024;
constexpr int BH      = BATCH * HID;   // 32768
constexpr int NBLK    = 256;

typedef __attribute__((ext_vector_type(8))) short    short8;
typedef __attribute__((ext_vector_type(4))) float    f32x4;
typedef __attribute__((ext_vector_type(4))) unsigned uint32x4;

__device__ __forceinline__ unsigned short f2bf(float f) {
    union { float f; unsigned u; } x; x.f = f;
    unsigned r = (x.u + 0x7fffu + ((x.u >> 16) & 1u)) >> 16;
    return (unsigned short)r;
}
__device__ __forceinline__ float bf2f(unsigned short h) {
    union { unsigned u; float f; } x; x.u = ((unsigned)h) << 16;
    return x.f;
}
__device__ __forceinline__ f32x4 mfma16(short8 a, short8 b, f32x4 c) {
    return __builtin_amdgcn_mfma_f32_16x16x32_bf16(a, b, c, 0, 0, 0);
}
__device__ __forceinline__ unsigned rmw_add_rlx(unsigned* p, unsigned v) {
    return __hip_atomic_fetch_add(p, v, __ATOMIC_RELAXED, __HIP_MEMORY_SCOPE_AGENT);
}
__device__ __forceinline__ unsigned flag_ld(const unsigned* p) {
    return __hip_atomic_load(p, __ATOMIC_RELAXED, __HIP_MEMORY_SCOPE_AGENT);
}
__device__ __forceinline__ float sigmoid_fast(float x) {
    return 1.0f / (1.0f + __expf(-x));
}
__device__ __forceinline__ float tanh_fast(float x) {
    const float t = __expf(-2.0f * fabsf(x));
    const float r = (1.0f - t) / (1.0f + t);
    return copysignf(r, x);
}
// Agent-coherent 16B load (bypasses L1/L2 like agent-scope atomics).
__device__ __forceinline__ uint32x4 cp_load4(const unsigned* p) {
    uint32x4 r;
    asm volatile("global_load_dwordx4 %0, %1, off sc0 sc1"
                 : "=v"(r) : "v"(p));
    return r;
}

// ---------------- one-time converters ----------------

__global__ void convert_split(const float* __restrict__ src,
                              unsigned short* __restrict__ hi,
                              unsigned short* __restrict__ lo, int n4) {
    for (int i = blockIdx.x * blockDim.x + threadIdx.x; i < n4;
         i += gridDim.x * blockDim.x) {
        const float4 v = ((const float4*)src)[i];
        ushort4 h, l;
        float t;
        h.x = f2bf(v.x); t = v.x - bf2f(h.x); l.x = f2bf(t);
        h.y = f2bf(v.y); t = v.y - bf2f(h.y); l.y = f2bf(t);
        h.z = f2bf(v.z); t = v.z - bf2f(h.z); l.z = f2bf(t);
        h.w = f2bf(v.w); t = v.w - bf2f(h.w); l.w = f2bf(t);
        ((ushort4*)hi)[i] = h;
        ((ushort4*)lo)[i] = l;
    }
}

// Wpk[blk][half(hi=0,lo=1)][kstep 0..63][lane 0..63][8 elems].
__global__ void pack_W(const float* __restrict__ W_ih,
                       const float* __restrict__ W_hh,
                       unsigned short* __restrict__ Wpk) {
    const int i = blockIdx.x * blockDim.x + threadIdx.x;   // 0 .. 2,097,151
    const int lane = i & 63;
    const int s    = (i >> 6) & 63;
    const int half = (i >> 12) & 1;
    const int blk  = i >> 13;
    if (blk >= NBLK) return;
    const int m   = lane & 15;
    const int kg  = (lane >> 4) << 3;
    const int row = ((m >> 2) << 10) + (blk << 2) + (m & 3);
    const int k   = (s << 5) + kg;
    const float* src = (k < IN_DIM) ? (W_ih + (size_t)row * IN_DIM + k)
                                    : (W_hh + (size_t)row * HID + (k - IN_DIM));
    unsigned short v[8];
    #pragma unroll
    for (int e = 0; e < 8; ++e) {
        const float f = src[e];
        const unsigned short h = f2bf(f);
        v[e] = half ? f2bf(f - bf2f(h)) : h;
    }
    ushort4* dst = (ushort4*)(Wpk + (size_t)i * 8);
    dst[0] = make_ushort4(v[0], v[1], v[2], v[3]);
    dst[1] = make_ushort4(v[4], v[5], v[6], v[7]);
}

// h0 pack into SLOT 2 of the ring; bias combine; pdone + bar reset.
__global__ void prep_state(const float* __restrict__ h0,
                           const float* __restrict__ b_ih,
                           const float* __restrict__ b_hh,
                           unsigned* __restrict__ h_slot2,
                           float* __restrict__ bias,
                           unsigned* __restrict__ pdone,
                           unsigned* __restrict__ bar) {
    const int i = blockIdx.x * blockDim.x + threadIdx.x;
    if (i < BH) {
        const float v = h0[i];
        const unsigned short hh = f2bf(v);
        const unsigned short hl = f2bf(v - bf2f(hh));
        h_slot2[i] = ((unsigned)hh << 16) | (unsigned)hl;
    }
    if (i < 4 * HID) bias[i] = b_ih[i] + b_hh[i];
    if (i < 1024) pdone[i] = 0u;
    if (i < 4096) bar[i] = 0u;
}

// ---------------- persistent LSTM scan ----------------
// Dynamic LDS: [0,128K) W; [128K,144K) reduce float[16][256].
// pdone[blk*4] (16B padded): monotonic publish count of block blk.
// bar[]: gcnt[g]=bar[g*64] (g=blk&15), gph[g]=bar[1024+g*64], rcnt=bar[2048]
//   -- consumption barrier only (backward edge).
__global__ __launch_bounds__(512, 2) void lstm_persistent(
    const unsigned short* __restrict__ x_hi,   // [T][32][1024]
    const unsigned short* __restrict__ x_lo,
    const unsigned short* __restrict__ Wpk,    // [256][2][64][64][8]
    unsigned* __restrict__ hring,              // 3 slots x [32][1024] packed
    const float* __restrict__ bias,            // [4096]
    const float* __restrict__ c0,              // [32][1024]
    float* __restrict__ out,
    unsigned* __restrict__ pdone,
    unsigned* __restrict__ bar)
{
    extern __shared__ unsigned char smem[];
    float* red = (float*)(smem + 131072);

    const int tid  = threadIdx.x;
    const int wave = tid >> 6;
    const int lane = tid & 63;
    const int blk  = blockIdx.x;

    // One-time: copy this block's 128 KiB W slice into LDS (coalesced).
    {
        const uint4* src = (const uint4*)Wpk + (size_t)blk * 8192;
        uint4* dst = (uint4*)smem;
        #pragma unroll
        for (int r = 0; r < 16; ++r) dst[r * 512 + tid] = src[r * 512 + tid];
    }

    const int m16    = lane & 15;
    const int kg     = (lane >> 4) << 3;
    const int off_b0 = m16 * HID + (wave << 7) + kg;   // frag base, b 0-15
    const int off_b1 = off_b0 + 16 * HID;              // b 16-31
    const int wbyte  = lane << 4;

    // Per-thread persistent epilogue state (tid < 128): c + bias.
    float c_reg = 0.f;
    float bias_reg[4] = {0.f, 0.f, 0.f, 0.f};
    const int b_own   = tid >> 2;
    const int jj      = tid & 3;
    const int col_own = (blk << 2) + jj;
    const int idx_own = b_own * HID + col_own;
    if (tid < 128) {
        #pragma unroll
        for (int g = 0; g < 4; ++g) bias_reg[g] = bias[g * HID + col_own];
        c_reg = c0[idx_own];
    }

    unsigned* const gcnt   = bar + ((blk & 15) * 64);
    unsigned* const gph_my = bar + 1024 + ((blk & 15) * 64);
    unsigned* const rcnt   = bar + 2048;
    // This wave's 32 producer flags: blocks wave*32 .. wave*32+31.
    const unsigned* const my_pf = pdone + (((wave << 5) + (lane & 31)) << 2);

    __syncthreads();

    // Prefetch x fragments for the first step.
    short8 pxh0[4], pxh1[4], pxl0[4], pxl1[4];
    {
        const unsigned short* xh = x_hi + (size_t)(T_STEPS - 1) * BH;
        const unsigned short* xl = x_lo + (size_t)(T_STEPS - 1) * BH;
        #pragma unroll
        for (int sq = 0; sq < 4; ++sq) {
            pxh0[sq] = *(const short8*)(xh + off_b0 + (sq << 5));
            pxh1[sq] = *(const short8*)(xh + off_b1 + (sq << 5));
            pxl0[sq] = *(const short8*)(xl + off_b0 + (sq << 5));
            pxl1[sq] = *(const short8*)(xl + off_b1 + (sq << 5));
        }
    }

    int wslot = 0, rslot = 2;   // step i writes slot i%3, reads (i+2)%3

    for (int i = 0; i < T_STEPS; ++i) {
        const int t = T_STEPS - 1 - i;
        unsigned* const hin  = hring + (size_t)rslot * BH;
        unsigned* const hout = hring + (size_t)wslot * BH;

        f32x4 acc0 = {0.f, 0.f, 0.f, 0.f};
        f32x4 acc1 = {0.f, 0.f, 0.f, 0.f};

        // x-part MFMAs (independent of h -> overlap the producer wait).
        #pragma unroll
        for (int sq = 0; sq < 4; ++sq) {
            const int s = (wave << 2) + sq;
            const short8 whi = *(const short8*)(smem + (size_t)s * 1024 + wbyte);
            const short8 wlo = *(const short8*)(smem + (size_t)(64 + s) * 1024 + wbyte);
            acc0 = mfma16(whi, pxh0[sq], acc0);
            acc0 = mfma16(whi, pxl0[sq], acc0);
            acc0 = mfma16(wlo, pxh0[sq], acc0);
            acc1 = mfma16(whi, pxh1[sq], acc1);
            acc1 = mfma16(whi, pxl1[sq], acc1);
            acc1 = mfma16(wlo, pxh1[sq], acc1);
        }

        // Issue next-step x prefetch (completes under wait/compute).
        if (i + 1 < T_STEPS) {
            const unsigned short* xh = x_hi + (size_t)(t - 1) * BH;
            const unsigned short* xl = x_lo + (size_t)(t - 1) * BH;
            #pragma unroll
            for (int sq = 0; sq < 4; ++sq) {
                pxh0[sq] = *(const short8*)(xh + off_b0 + (sq << 5));
                pxh1[sq] = *(const short8*)(xh + off_b1 + (sq << 5));
                pxl0[sq] = *(const short8*)(xl + off_b0 + (sq << 5));
                pxl1[sq] = *(const short8*)(xl + off_b1 + (sq << 5));
            }
        }

        // FORWARD WAIT: this wave's 32 producers published step i-1?
        if (i > 0) {
            int spins = 0;
            while (!__all(flag_ld(my_pf) >= (unsigned)i)) {
                __builtin_amdgcn_s_sleep(1);
                if (++spins > (1 << 22)) break;   // break -> absmax fail, not hang
            }
            asm volatile("" ::: "memory");
        }

        // h loads: 16 coherent dwordx4 (sc0 sc1) per lane, issued
        // back-to-back; one vmcnt(0) + sched_barrier(0) [rule #18].
        uint32x4 hv0[8], hv1[8];
        #pragma unroll
        for (int sq = 0; sq < 4; ++sq) {
            const unsigned* p0 = hin + off_b0 + (sq << 5);
            const unsigned* p1 = hin + off_b1 + (sq << 5);
            hv0[sq * 2]     = cp_load4(p0);
            hv0[sq * 2 + 1] = cp_load4(p0 + 4);
            hv1[sq * 2]     = cp_load4(p1);
            hv1[sq * 2 + 1] = cp_load4(p1 + 4);
        }
        asm volatile("s_waitcnt vmcnt(0)" ::: "memory");
        __builtin_amdgcn_sched_barrier(0);

        // h-part MFMAs from registers.
        #pragma unroll
        for (int sq = 0; sq < 4; ++sq) {
            const int s = 32 + (wave << 2) + sq;
            const short8 whi = *(const short8*)(smem + (size_t)s * 1024 + wbyte);
            const short8 wlo = *(const short8*)(smem + (size_t)(64 + s) * 1024 + wbyte);
            short8 hh0, hl0, hh1, hl1;
            const uint32x4 a0v = hv0[sq * 2], b0v = hv0[sq * 2 + 1];
            const uint32x4 a1v = hv1[sq * 2], b1v = hv1[sq * 2 + 1];
            #pragma unroll
            for (int e = 0; e < 4; ++e) {
                hh0[e]     = (short)(a0v[e] >> 16); hl0[e]     = (short)(a0v[e] & 0xffffu);
                hh0[e + 4] = (short)(b0v[e] >> 16); hl0[e + 4] = (short)(b0v[e] & 0xffffu);
                hh1[e]     = (short)(a1v[e] >> 16); hl1[e]     = (short)(a1v[e] & 0xffffu);
                hh1[e + 4] = (short)(b1v[e] >> 16); hl1[e + 4] = (short)(b1v[e] & 0xffffu);
            }
            acc0 = mfma16(whi, hh0, acc0);
            acc0 = mfma16(whi, hl0, acc0);
            acc0 = mfma16(wlo, hh0, acc0);
            acc1 = mfma16(whi, hh1, acc1);
            acc1 = mfma16(whi, hl1, acc1);
            acc1 = mfma16(wlo, hh1, acc1);
        }

        // Cross-wave reduce. C/D layout (m89): col=lane&15, row=4*(lane>>4)+r.
        {
            const int arow = (lane >> 4) << 2;
            const int acol = lane & 15;
            #pragma unroll
            for (int r = 0; r < 4; ++r) {
                red[((wave << 1) + 0) * 256 + (arow + r) * 16 + acol] = acc0[r];
                red[((wave << 1) + 1) * 256 + (arow + r) * 16 + acol] = acc1[r];
            }
        }
        __syncthreads();   // (A) all h-MFMAs done; red[] ready

        // Consumption arrival (backward edge): monotonic tree + broadcast.
        if (tid == 0) {
            const unsigned a = rmw_add_rlx(gcnt, 1u);
            if ((a & 15u) == 15u) {               // group finisher
                const unsigned r = rmw_add_rlx(rcnt, 1u);
                if ((r & 15u) == 15u) {           // grid finisher: broadcast
                    #pragma unroll
                    for (int g = 0; g < 16; ++g)
                        __hip_atomic_store(bar + 1024 + g * 64, (unsigned)(i + 1),
                                           __ATOMIC_RELAXED,
                                           __HIP_MEMORY_SCOPE_AGENT);
                }
            }
        }

        if (tid < 128) {
            const int mt  = b_own >> 4;
            const int c16 = b_own & 15;
            float val[4];
            #pragma unroll
            for (int g = 0; g < 4; ++g) {
                const int rr = ((g << 2) + jj) * 16 + c16;
                float sacc = 0.f;
                #pragma unroll
                for (int w = 0; w < 8; ++w) sacc += red[((w << 1) + mt) * 256 + rr];
                val[g] = sacc + bias_reg[g];
            }
            const float ig = sigmoid_fast(val[0]);
            const float fg = sigmoid_fast(val[1]);
            const float gg = tanh_fast(val[2]);
            const float og = sigmoid_fast(val[3]);
            c_reg = fg * c_reg + ig * gg;
            const float h_new = og * tanh_fast(c_reg);
            out[(size_t)t * BH + idx_own] = h_new;               // plain cached
            if (t == 0) out[(size_t)T_STEPS * BH + idx_own] = h_new;  // h_fin

            // BACKWARD CHECK (pre-satisfied; ~1.5 step slack).
            if (i >= 2) {
                int spins = 0;
                while (flag_ld(gph_my) < (unsigned)(i - 1)) {
                    __builtin_amdgcn_s_sleep(1);
                    if (++spins > 16384) {
                        if (rmw_add_rlx(gph_my, 0u) >= (unsigned)(i - 1)) break;
                        spins = 8192;
                    }
                }
            }
            const unsigned short hh = f2bf(h_new);
            const unsigned short hl = f2bf(h_new - bf2f(hh));
            __hip_atomic_store(hout + idx_own,
                               ((unsigned)hh << 16) | (unsigned)hl,
                               __ATOMIC_RELAXED, __HIP_MEMORY_SCOPE_AGENT);
        }
        __syncthreads();   // (C) drain all h stores (vmcnt=0 before s_barrier)

        // Publish: this block's h slice for step i is at the CP.
        if (tid == 0)
            __hip_atomic_store(pdone + (blk << 2), (unsigned)(i + 1),
                               __ATOMIC_RELAXED, __HIP_MEMORY_SCOPE_AGENT);

        wslot = (wslot == 2) ? 0 : wslot + 1;
        rslot = (rslot == 2) ? 0 : rslot + 1;
    }

    if (tid < 128)
        out[(size_t)T_STEPS * BH + BH + idx_own] = c_reg;   // c_fin
}

// ---------------- fallback (round-1, known-good, slow) ----------------
__global__ __launch_bounds__(256) void lstm_step_fused(
    const float* __restrict__ x_t, const float* __restrict__ h_prev,
    const float* __restrict__ c_prev, float* __restrict__ c_out,
    float* __restrict__ h_out, const float* __restrict__ W_ih,
    const float* __restrict__ W_hh, const float* __restrict__ b_ih,
    const float* __restrict__ b_hh) {
    __shared__ float xs[IN_DIM];
    __shared__ float hs[HID];
    const int tid = threadIdx.x;
    const int b   = blockIdx.x >> 2;
    const int j   = ((blockIdx.x & 3) << 8) | tid;
    ((float4*)xs)[tid] = ((const float4*)(x_t    + (size_t)b * IN_DIM))[tid];
    ((float4*)hs)[tid] = ((const float4*)(h_prev + (size_t)b * HID))[tid];
    __syncthreads();
    float a0 = b_ih[j] + b_hh[j];
    float a1 = b_ih[HID + j] + b_hh[HID + j];
    float a2 = b_ih[2*HID + j] + b_hh[2*HID + j];
    float a3 = b_ih[3*HID + j] + b_hh[3*HID + j];
    {
        const float4* wi0 = (const float4*)(W_ih + (size_t)(0*HID + j) * IN_DIM);
        const float4* wi1 = (const float4*)(W_ih + (size_t)(1*HID + j) * IN_DIM);
        const float4* wi2 = (const float4*)(W_ih + (size_t)(2*HID + j) * IN_DIM);
        const float4* wi3 = (const float4*)(W_ih + (size_t)(3*HID + j) * IN_DIM);
        const float4* xs4 = (const float4*)xs;
        #pragma unroll 4
        for (int k = 0; k < IN_DIM / 4; ++k) {
            const float4 xv = xs4[k]; float4 w;
            w = wi0[k]; a0 += xv.x*w.x + xv.y*w.y + xv.z*w.z + xv.w*w.w;
            w = wi1[k]; a1 += xv.x*w.x + xv.y*w.y + xv.z*w.z + xv.w*w.w;
            w = wi2[k]; a2 += xv.x*w.x + xv.y*w.y + xv.z*w.z + xv.w*w.w;
            w = wi3[k]; a3 += xv.x*w.x + xv.y*w.y + xv.z*w.z + xv.w*w.w;
        }
    }
    {
        const float4* wh0 = (const float4*)(W_hh + (size_t)(0*HID + j) * HID);
        const float4* wh1 = (const float4*)(W_hh + (size_t)(1*HID + j) * HID);
        const float4* wh2 = (const float4*)(W_hh + (size_t)(2*HID + j) * HID);
        const float4* wh3 = (const float4*)(W_hh + (size_t)(3*HID + j) * HID);
        const float4* hs4 = (const float4*)hs;
        #pragma unroll 4
        for (int k = 0; k < HID / 4; ++k) {
            const float4 hv = hs4[k]; float4 w;
            w = wh0[k]; a0 += hv.x*w.x + hv.y*w.y + hv.z*w.z + hv.w*w.w;
            w = wh1[k]; a1 += hv.x*w.x + hv.y*w.y + hv.z*w.z + hv.w*w.w;
            w = wh2[k]; a2 += hv.x*w.x + hv.y*w.y + hv.z*w.z + hv.w*w.w;
            w = wh3[k]; a3 += hv.x*w.x + hv.y*w.y + hv.z*w.z + hv.w*w.w;
        }
    }
    const float ig = 1.0f / (1.0f + __expf(-a0));
    const float fg = 1.0f / (1.0f + __expf(-a1));
    const float gg = tanhf(a2);
    const float og = 1.0f / (1.0f + __expf(-a3));
    const size_t idx = (size_t)b * HID + j;
    const float c_new = fg * c_prev[idx] + ig * gg;
    c_out[idx] = c_new;
    h_out[idx] = og * tanhf(c_new);
}

__global__ void lstm_finalize(const float* __restrict__ h_fin_src,
                              const float* __restrict__ c_fin_src,
                              float* __restrict__ dst_h,
                              float* __restrict__ dst_c) {
    const int i = blockIdx.x * blockDim.x + threadIdx.x;
    if (i < BH) { dst_h[i] = h_fin_src[i]; dst_c[i] = c_fin_src[i]; }
}

// ---------------- host ----------------

extern "C" void kernel_launch(void* const* d_in, const int* in_sizes, int n_in,
                              void* d_out, int out_size, void* d_ws, size_t ws_size,
                              hipStream_t stream) {
    const float* input = (const float*)d_in[0];
    const float* h0    = (const float*)d_in[1];
    const float* c0    = (const float*)d_in[2];
    const float* W_ih  = (const float*)d_in[3];
    const float* W_hh  = (const float*)d_in[4];
    const float* b_ih  = (const float*)d_in[5];
    const float* b_hh  = (const float*)d_in[6];
    float* out = (float*)d_out;

    // ws carve-up (bytes)
    const size_t OFF_XHI   = 0;                         // 64 MiB
    const size_t OFF_XLO   = OFF_XHI + 67108864ULL;     // 64 MiB
    const size_t OFF_WPK   = OFF_XLO + 67108864ULL;     // 32 MiB
    const size_t OFF_BIAS  = OFF_WPK + 33554432ULL;     // 16 KiB
    const size_t OFF_HR    = OFF_BIAS + 16384ULL;       // 3 x 128 KiB h ring
    const size_t OFF_PD    = OFF_HR + 3 * 131072ULL;    // 4 KiB pdone
    const size_t OFF_BAR   = OFF_PD + 4096ULL;          // 16 KiB barrier
    const size_t NEED      = OFF_BAR + 16384ULL;

    if (ws_size >= NEED) {
        unsigned char* w = (unsigned char*)d_ws;
        unsigned short* x_hi  = (unsigned short*)(w + OFF_XHI);
        unsigned short* x_lo  = (unsigned short*)(w + OFF_XLO);
        unsigned short* Wpk   = (unsigned short*)(w + OFF_WPK);
        float*          bias  = (float*)(w + OFF_BIAS);
        unsigned*       hring = (unsigned*)(w + OFF_HR);
        unsigned*       pdone = (unsigned*)(w + OFF_PD);
        unsigned*       bar   = (unsigned*)(w + OFF_BAR);

        hipLaunchKernelGGL(convert_split, dim3(4096), dim3(256), 0, stream,
                           input, x_hi, x_lo, T_STEPS * BH / 4);
        hipLaunchKernelGGL(pack_W, dim3(8192), dim3(256), 0, stream,
                           W_ih, W_hh, Wpk);
        hipLaunchKernelGGL(prep_state, dim3(128), dim3(256), 0, stream,
                           h0, b_ih, b_hh, hring + 2 * (size_t)BH, bias,
                           pdone, bar);

        (void)hipFuncSetAttribute(reinterpret_cast<const void*>(lstm_persistent),
                                  hipFuncAttributeMaxDynamicSharedMemorySize, 147456);
        hipLaunchKernelGGL(lstm_persistent, dim3(NBLK), dim3(512), 147456, stream,
                           x_hi, x_lo, Wpk, hring, bias, c0, out, pdone, bar);
    } else {
        // fallback: round-1 path (c scratch only)
        float* c_ws = (float*)d_ws;
        for (int t = T_STEPS - 1; t >= 0; --t) {
            const float* x_t = input + (size_t)t * BATCH * IN_DIM;
            const float* hp  = (t == T_STEPS - 1) ? h0 : out + (size_t)(t + 1) * BH;
            const float* cp  = (t == T_STEPS - 1) ? c0 : c_ws;
            hipLaunchKernelGGL(lstm_step_fused, dim3(128), dim3(256), 0, stream,
                               x_t, hp, cp, c_ws, out + (size_t)t * BH,
                               W_ih, W_hh, b_ih, b_hh);
        }
        hipLaunchKernelGGL(lstm_finalize, dim3(128), dim3(256), 0, stream,
                           out, c_ws,
                           out + (size_t)T_STEPS * BH,
                           out + (size_t)T_STEPS * BH + BH);
    }
}

// Round 13
// 7536.501 us; speedup vs baseline: 2.6887x; 1.2391x over previous
//
#include <hip/hip_runtime.h>

// ReverseLSTMLayer: T=1024, B=32, I=1024, H=1024, fp32 in/out.
// d_out layout: outputs [T*B*H] | h_fin [B*H] | c_fin [B*H].
//
// Round 13 = round 12 with ONE change: h exchanged as bf16-HI ONLY (u16).
//  - h ring slots are [32][1024] ushort (64 KB); per-lane h reads drop to
//    8 dwordx4 (the 16B loaded IS the short8 MFMA fragment; unpack gone).
//  - h-MFMAs per sq: 2 (whi*hh + wlo*hh); the whi*hl term is dropped --
//    error model ~0.001-0.002/step pre-activation, damped by f-gates;
//    absmax headroom is 10x (0.0039 vs threshold 0.0398).
//  - Store side: epilogue pairs (tid, tid^1) pack two adjacent cols' bf16
//    via __shfl_xor -> 64 coalesced u32 agent stores per block.
// x and W stay full split-bf16 3-pass. Forward pdone flags, 3-slot ring,
// backward tree barrier, no fences -- all as round 12.

constexpr int T_STEPS = 1024;
constexpr int BATCH   = 32;
constexpr int IN_DIM  = 1024;
constexpr int HID     = 1024;
constexpr int BH      = BATCH * HID;   // 32768
constexpr int NBLK    = 256;

typedef __attribute__((ext_vector_type(8))) short    short8;
typedef __attribute__((ext_vector_type(4))) float    f32x4;
typedef __attribute__((ext_vector_type(4))) unsigned uint32x4;

__device__ __forceinline__ unsigned short f2bf(float f) {
    union { float f; unsigned u; } x; x.f = f;
    unsigned r = (x.u + 0x7fffu + ((x.u >> 16) & 1u)) >> 16;
    return (unsigned short)r;
}
__device__ __forceinline__ float bf2f(unsigned short h) {
    union { unsigned u; float f; } x; x.u = ((unsigned)h) << 16;
    return x.f;
}
__device__ __forceinline__ f32x4 mfma16(short8 a, short8 b, f32x4 c) {
    return __builtin_amdgcn_mfma_f32_16x16x32_bf16(a, b, c, 0, 0, 0);
}
__device__ __forceinline__ unsigned rmw_add_rlx(unsigned* p, unsigned v) {
    return __hip_atomic_fetch_add(p, v, __ATOMIC_RELAXED, __HIP_MEMORY_SCOPE_AGENT);
}
__device__ __forceinline__ unsigned flag_ld(const unsigned* p) {
    return __hip_atomic_load(p, __ATOMIC_RELAXED, __HIP_MEMORY_SCOPE_AGENT);
}
__device__ __forceinline__ float sigmoid_fast(float x) {
    return 1.0f / (1.0f + __expf(-x));
}
__device__ __forceinline__ float tanh_fast(float x) {
    const float t = __expf(-2.0f * fabsf(x));
    const float r = (1.0f - t) / (1.0f + t);
    return copysignf(r, x);
}
// Agent-coherent 16B load (CP-fresh, like agent-scope atomics).
__device__ __forceinline__ uint32x4 cp_load4(const void* p) {
    uint32x4 r;
    asm volatile("global_load_dwordx4 %0, %1, off sc0 sc1"
                 : "=v"(r) : "v"(p));
    return r;
}

// ---------------- one-time converters ----------------

__global__ void convert_split(const float* __restrict__ src,
                              unsigned short* __restrict__ hi,
                              unsigned short* __restrict__ lo, int n4) {
    for (int i = blockIdx.x * blockDim.x + threadIdx.x; i < n4;
         i += gridDim.x * blockDim.x) {
        const float4 v = ((const float4*)src)[i];
        ushort4 h, l;
        float t;
        h.x = f2bf(v.x); t = v.x - bf2f(h.x); l.x = f2bf(t);
        h.y = f2bf(v.y); t = v.y - bf2f(h.y); l.y = f2bf(t);
        h.z = f2bf(v.z); t = v.z - bf2f(h.z); l.z = f2bf(t);
        h.w = f2bf(v.w); t = v.w - bf2f(h.w); l.w = f2bf(t);
        ((ushort4*)hi)[i] = h;
        ((ushort4*)lo)[i] = l;
    }
}

// Wpk[blk][half(hi=0,lo=1)][kstep 0..63][lane 0..63][8 elems].
__global__ void pack_W(const float* __restrict__ W_ih,
                       const float* __restrict__ W_hh,
                       unsigned short* __restrict__ Wpk) {
    const int i = blockIdx.x * blockDim.x + threadIdx.x;   // 0 .. 2,097,151
    const int lane = i & 63;
    const int s    = (i >> 6) & 63;
    const int half = (i >> 12) & 1;
    const int blk  = i >> 13;
    if (blk >= NBLK) return;
    const int m   = lane & 15;
    const int kg  = (lane >> 4) << 3;
    const int row = ((m >> 2) << 10) + (blk << 2) + (m & 3);
    const int k   = (s << 5) + kg;
    const float* src = (k < IN_DIM) ? (W_ih + (size_t)row * IN_DIM + k)
                                    : (W_hh + (size_t)row * HID + (k - IN_DIM));
    unsigned short v[8];
    #pragma unroll
    for (int e = 0; e < 8; ++e) {
        const float f = src[e];
        const unsigned short h = f2bf(f);
        v[e] = half ? f2bf(f - bf2f(h)) : h;
    }
    ushort4* dst = (ushort4*)(Wpk + (size_t)i * 8);
    dst[0] = make_ushort4(v[0], v[1], v[2], v[3]);
    dst[1] = make_ushort4(v[4], v[5], v[6], v[7]);
}

// h0 -> bf16-hi into SLOT 2 of the ring; bias combine; pdone + bar reset.
__global__ void prep_state(const float* __restrict__ h0,
                           const float* __restrict__ b_ih,
                           const float* __restrict__ b_hh,
                           unsigned short* __restrict__ h_slot2,
                           float* __restrict__ bias,
                           unsigned* __restrict__ pdone,
                           unsigned* __restrict__ bar) {
    const int i = blockIdx.x * blockDim.x + threadIdx.x;
    if (i < BH) h_slot2[i] = f2bf(h0[i]);
    if (i < 4 * HID) bias[i] = b_ih[i] + b_hh[i];
    if (i < 1024) pdone[i] = 0u;
    if (i < 4096) bar[i] = 0u;
}

// ---------------- persistent LSTM scan ----------------
// Dynamic LDS: [0,128K) W; [128K,144K) reduce float[16][256].
// pdone[blk*4] (16B padded): monotonic publish count of block blk.
// bar[]: gcnt[g]=bar[g*64] (g=blk&15), gph[g]=bar[1024+g*64], rcnt=bar[2048]
//   -- consumption barrier only (backward edge).
__global__ __launch_bounds__(512, 2) void lstm_persistent(
    const unsigned short* __restrict__ x_hi,   // [T][32][1024]
    const unsigned short* __restrict__ x_lo,
    const unsigned short* __restrict__ Wpk,    // [256][2][64][64][8]
    unsigned short* __restrict__ hring,        // 3 slots x [32][1024] bf16-hi
    const float* __restrict__ bias,            // [4096]
    const float* __restrict__ c0,              // [32][1024]
    float* __restrict__ out,
    unsigned* __restrict__ pdone,
    unsigned* __restrict__ bar)
{
    extern __shared__ unsigned char smem[];
    float* red = (float*)(smem + 131072);

    const int tid  = threadIdx.x;
    const int wave = tid >> 6;
    const int lane = tid & 63;
    const int blk  = blockIdx.x;

    // One-time: copy this block's 128 KiB W slice into LDS (coalesced).
    {
        const uint4* src = (const uint4*)Wpk + (size_t)blk * 8192;
        uint4* dst = (uint4*)smem;
        #pragma unroll
        for (int r = 0; r < 16; ++r) dst[r * 512 + tid] = src[r * 512 + tid];
    }

    const int m16    = lane & 15;
    const int kg     = (lane >> 4) << 3;
    const int off_b0 = m16 * HID + (wave << 7) + kg;   // frag base, b 0-15
    const int off_b1 = off_b0 + 16 * HID;              // b 16-31
    const int wbyte  = lane << 4;

    // Per-thread persistent epilogue state (tid < 128): c + bias.
    float c_reg = 0.f;
    float bias_reg[4] = {0.f, 0.f, 0.f, 0.f};
    const int b_own   = tid >> 2;
    const int jj      = tid & 3;
    const int col_own = (blk << 2) + jj;
    const int idx_own = b_own * HID + col_own;
    if (tid < 128) {
        #pragma unroll
        for (int g = 0; g < 4; ++g) bias_reg[g] = bias[g * HID + col_own];
        c_reg = c0[idx_own];
    }

    unsigned* const gcnt   = bar + ((blk & 15) * 64);
    unsigned* const gph_my = bar + 1024 + ((blk & 15) * 64);
    unsigned* const rcnt   = bar + 2048;
    // This wave's 32 producer flags: blocks wave*32 .. wave*32+31.
    const unsigned* const my_pf = pdone + (((wave << 5) + (lane & 31)) << 2);

    __syncthreads();

    // Prefetch x fragments for the first step.
    short8 pxh0[4], pxh1[4], pxl0[4], pxl1[4];
    {
        const unsigned short* xh = x_hi + (size_t)(T_STEPS - 1) * BH;
        const unsigned short* xl = x_lo + (size_t)(T_STEPS - 1) * BH;
        #pragma unroll
        for (int sq = 0; sq < 4; ++sq) {
            pxh0[sq] = *(const short8*)(xh + off_b0 + (sq << 5));
            pxh1[sq] = *(const short8*)(xh + off_b1 + (sq << 5));
            pxl0[sq] = *(const short8*)(xl + off_b0 + (sq << 5));
            pxl1[sq] = *(const short8*)(xl + off_b1 + (sq << 5));
        }
    }

    int wslot = 0, rslot = 2;   // step i writes slot i%3, reads (i+2)%3

    for (int i = 0; i < T_STEPS; ++i) {
        const int t = T_STEPS - 1 - i;
        unsigned short* const hin  = hring + (size_t)rslot * BH;
        unsigned short* const hout = hring + (size_t)wslot * BH;

        f32x4 acc0 = {0.f, 0.f, 0.f, 0.f};
        f32x4 acc1 = {0.f, 0.f, 0.f, 0.f};

        // x-part MFMAs (independent of h -> overlap the producer wait).
        #pragma unroll
        for (int sq = 0; sq < 4; ++sq) {
            const int s = (wave << 2) + sq;
            const short8 whi = *(const short8*)(smem + (size_t)s * 1024 + wbyte);
            const short8 wlo = *(const short8*)(smem + (size_t)(64 + s) * 1024 + wbyte);
            acc0 = mfma16(whi, pxh0[sq], acc0);
            acc0 = mfma16(whi, pxl0[sq], acc0);
            acc0 = mfma16(wlo, pxh0[sq], acc0);
            acc1 = mfma16(whi, pxh1[sq], acc1);
            acc1 = mfma16(whi, pxl1[sq], acc1);
            acc1 = mfma16(wlo, pxh1[sq], acc1);
        }

        // Issue next-step x prefetch (completes under wait/compute).
        if (i + 1 < T_STEPS) {
            const unsigned short* xh = x_hi + (size_t)(t - 1) * BH;
            const unsigned short* xl = x_lo + (size_t)(t - 1) * BH;
            #pragma unroll
            for (int sq = 0; sq < 4; ++sq) {
                pxh0[sq] = *(const short8*)(xh + off_b0 + (sq << 5));
                pxh1[sq] = *(const short8*)(xh + off_b1 + (sq << 5));
                pxl0[sq] = *(const short8*)(xl + off_b0 + (sq << 5));
                pxl1[sq] = *(const short8*)(xl + off_b1 + (sq << 5));
            }
        }

        // FORWARD WAIT: this wave's 32 producers published step i-1?
        if (i > 0) {
            int spins = 0;
            while (!__all(flag_ld(my_pf) >= (unsigned)i)) {
                __builtin_amdgcn_s_sleep(1);
                if (++spins > (1 << 22)) break;   // break -> absmax fail, not hang
            }
            asm volatile("" ::: "memory");
        }

        // h loads: 8 coherent dwordx4 per lane -- each IS a short8 hi-frag.
        uint32x4 hv0[4], hv1[4];
        #pragma unroll
        for (int sq = 0; sq < 4; ++sq) {
            hv0[sq] = cp_load4(hin + off_b0 + (sq << 5));
            hv1[sq] = cp_load4(hin + off_b1 + (sq << 5));
        }
        asm volatile("s_waitcnt vmcnt(0)" ::: "memory");
        __builtin_amdgcn_sched_barrier(0);

        // h-part MFMAs (2-pass: whi*hh + wlo*hh).
        #pragma unroll
        for (int sq = 0; sq < 4; ++sq) {
            const int s = 32 + (wave << 2) + sq;
            const short8 whi = *(const short8*)(smem + (size_t)s * 1024 + wbyte);
            const short8 wlo = *(const short8*)(smem + (size_t)(64 + s) * 1024 + wbyte);
            const short8 hh0 = *(const short8*)&hv0[sq];
            const short8 hh1 = *(const short8*)&hv1[sq];
            acc0 = mfma16(whi, hh0, acc0);
            acc0 = mfma16(wlo, hh0, acc0);
            acc1 = mfma16(whi, hh1, acc1);
            acc1 = mfma16(wlo, hh1, acc1);
        }

        // Cross-wave reduce. C/D layout (m89): col=lane&15, row=4*(lane>>4)+r.
        {
            const int arow = (lane >> 4) << 2;
            const int acol = lane & 15;
            #pragma unroll
            for (int r = 0; r < 4; ++r) {
                red[((wave << 1) + 0) * 256 + (arow + r) * 16 + acol] = acc0[r];
                red[((wave << 1) + 1) * 256 + (arow + r) * 16 + acol] = acc1[r];
            }
        }
        __syncthreads();   // (A) all h-MFMAs done; red[] ready

        // Consumption arrival (backward edge): monotonic tree + broadcast.
        if (tid == 0) {
            const unsigned a = rmw_add_rlx(gcnt, 1u);
            if ((a & 15u) == 15u) {               // group finisher
                const unsigned r = rmw_add_rlx(rcnt, 1u);
                if ((r & 15u) == 15u) {           // grid finisher: broadcast
                    #pragma unroll
                    for (int g = 0; g < 16; ++g)
                        __hip_atomic_store(bar + 1024 + g * 64, (unsigned)(i + 1),
                                           __ATOMIC_RELAXED,
                                           __HIP_MEMORY_SCOPE_AGENT);
                }
            }
        }

        if (tid < 128) {
            const int mt  = b_own >> 4;
            const int c16 = b_own & 15;
            float val[4];
            #pragma unroll
            for (int g = 0; g < 4; ++g) {
                const int rr = ((g << 2) + jj) * 16 + c16;
                float sacc = 0.f;
                #pragma unroll
                for (int w = 0; w < 8; ++w) sacc += red[((w << 1) + mt) * 256 + rr];
                val[g] = sacc + bias_reg[g];
            }
            const float ig = sigmoid_fast(val[0]);
            const float fg = sigmoid_fast(val[1]);
            const float gg = tanh_fast(val[2]);
            const float og = sigmoid_fast(val[3]);
            c_reg = fg * c_reg + ig * gg;
            const float h_new = og * tanh_fast(c_reg);
            out[(size_t)t * BH + idx_own] = h_new;               // plain cached
            if (t == 0) out[(size_t)T_STEPS * BH + idx_own] = h_new;  // h_fin

            // BACKWARD CHECK (pre-satisfied; ~1.5 step slack).
            if (i >= 2) {
                int spins = 0;
                while (flag_ld(gph_my) < (unsigned)(i - 1)) {
                    __builtin_amdgcn_s_sleep(1);
                    if (++spins > 16384) {
                        if (rmw_add_rlx(gph_my, 0u) >= (unsigned)(i - 1)) break;
                        spins = 8192;
                    }
                }
            }
            // Pair (tid, tid^1): same batch-row, adjacent cols -> one u32.
            const unsigned short hh = f2bf(h_new);
            const unsigned nb = __shfl_xor((unsigned)hh, 1);
            if ((jj & 1) == 0) {
                const unsigned pk = ((unsigned)hh) | (nb << 16);  // little-endian
                __hip_atomic_store((unsigned*)(hout + idx_own), pk,
                                   __ATOMIC_RELAXED, __HIP_MEMORY_SCOPE_AGENT);
            }
        }
        __syncthreads();   // (C) drain all h stores (vmcnt=0 before s_barrier)

        // Publish: this block's h slice for step i is at the CP.
        if (tid == 0)
            __hip_atomic_store(pdone + (blk << 2), (unsigned)(i + 1),
                               __ATOMIC_RELAXED, __HIP_MEMORY_SCOPE_AGENT);

        wslot = (wslot == 2) ? 0 : wslot + 1;
        rslot = (rslot == 2) ? 0 : rslot + 1;
    }

    if (tid < 128)
        out[(size_t)T_STEPS * BH + BH + idx_own] = c_reg;   // c_fin
}

// ---------------- fallback (round-1, known-good, slow) ----------------
__global__ __launch_bounds__(256) void lstm_step_fused(
    const float* __restrict__ x_t, const float* __restrict__ h_prev,
    const float* __restrict__ c_prev, float* __restrict__ c_out,
    float* __restrict__ h_out, const float* __restrict__ W_ih,
    const float* __restrict__ W_hh, const float* __restrict__ b_ih,
    const float* __restrict__ b_hh) {
    __shared__ float xs[IN_DIM];
    __shared__ float hs[HID];
    const int tid = threadIdx.x;
    const int b   = blockIdx.x >> 2;
    const int j   = ((blockIdx.x & 3) << 8) | tid;
    ((float4*)xs)[tid] = ((const float4*)(x_t    + (size_t)b * IN_DIM))[tid];
    ((float4*)hs)[tid] = ((const float4*)(h_prev + (size_t)b * HID))[tid];
    __syncthreads();
    float a0 = b_ih[j] + b_hh[j];
    float a1 = b_ih[HID + j] + b_hh[HID + j];
    float a2 = b_ih[2*HID + j] + b_hh[2*HID + j];
    float a3 = b_ih[3*HID + j] + b_hh[3*HID + j];
    {
        const float4* wi0 = (const float4*)(W_ih + (size_t)(0*HID + j) * IN_DIM);
        const float4* wi1 = (const float4*)(W_ih + (size_t)(1*HID + j) * IN_DIM);
        const float4* wi2 = (const float4*)(W_ih + (size_t)(2*HID + j) * IN_DIM);
        const float4* wi3 = (const float4*)(W_ih + (size_t)(3*HID + j) * IN_DIM);
        const float4* xs4 = (const float4*)xs;
        #pragma unroll 4
        for (int k = 0; k < IN_DIM / 4; ++k) {
            const float4 xv = xs4[k]; float4 w;
            w = wi0[k]; a0 += xv.x*w.x + xv.y*w.y + xv.z*w.z + xv.w*w.w;
            w = wi1[k]; a1 += xv.x*w.x + xv.y*w.y + xv.z*w.z + xv.w*w.w;
            w = wi2[k]; a2 += xv.x*w.x + xv.y*w.y + xv.z*w.z + xv.w*w.w;
            w = wi3[k]; a3 += xv.x*w.x + xv.y*w.y + xv.z*w.z + xv.w*w.w;
        }
    }
    {
        const float4* wh0 = (const float4*)(W_hh + (size_t)(0*HID + j) * HID);
        const float4* wh1 = (const float4*)(W_hh + (size_t)(1*HID + j) * HID);
        const float4* wh2 = (const float4*)(W_hh + (size_t)(2*HID + j) * HID);
        const float4* wh3 = (const float4*)(W_hh + (size_t)(3*HID + j) * HID);
        const float4* hs4 = (const float4*)hs;
        #pragma unroll 4
        for (int k = 0; k < HID / 4; ++k) {
            const float4 hv = hs4[k]; float4 w;
            w = wh0[k]; a0 += hv.x*w.x + hv.y*w.y + hv.z*w.z + hv.w*w.w;
            w = wh1[k]; a1 += hv.x*w.x + hv.y*w.y + hv.z*w.z + hv.w*w.w;
            w = wh2[k]; a2 += hv.x*w.x + hv.y*w.y + hv.z*w.z + hv.w*w.w;
            w = wh3[k]; a3 += hv.x*w.x + hv.y*w.y + hv.z*w.z + hv.w*w.w;
        }
    }
    const float ig = 1.0f / (1.0f + __expf(-a0));
    const float fg = 1.0f / (1.0f + __expf(-a1));
    const float gg = tanhf(a2);
    const float og = 1.0f / (1.0f + __expf(-a3));
    const size_t idx = (size_t)b * HID + j;
    const float c_new = fg * c_prev[idx] + ig * gg;
    c_out[idx] = c_new;
    h_out[idx] = og * tanhf(c_new);
}

__global__ void lstm_finalize(const float* __restrict__ h_fin_src,
                              const float* __restrict__ c_fin_src,
                              float* __restrict__ dst_h,
                              float* __restrict__ dst_c) {
    const int i = blockIdx.x * blockDim.x + threadIdx.x;
    if (i < BH) { dst_h[i] = h_fin_src[i]; dst_c[i] = c_fin_src[i]; }
}

// ---------------- host ----------------

extern "C" void kernel_launch(void* const* d_in, const int* in_sizes, int n_in,
                              void* d_out, int out_size, void* d_ws, size_t ws_size,
                              hipStream_t stream) {
    const float* input = (const float*)d_in[0];
    const float* h0    = (const float*)d_in[1];
    const float* c0    = (const float*)d_in[2];
    const float* W_ih  = (const float*)d_in[3];
    const float* W_hh  = (const float*)d_in[4];
    const float* b_ih  = (const float*)d_in[5];
    const float* b_hh  = (const float*)d_in[6];
    float* out = (float*)d_out;

    // ws carve-up (bytes)
    const size_t OFF_XHI   = 0;                         // 64 MiB
    const size_t OFF_XLO   = OFF_XHI + 67108864ULL;     // 64 MiB
    const size_t OFF_WPK   = OFF_XLO + 67108864ULL;     // 32 MiB
    const size_t OFF_BIAS  = OFF_WPK + 33554432ULL;     // 16 KiB
    const size_t OFF_HR    = OFF_BIAS + 16384ULL;       // 3 x 64 KiB h ring
    const size_t OFF_PD    = OFF_HR + 3 * 65536ULL;     // 4 KiB pdone
    const size_t OFF_BAR   = OFF_PD + 4096ULL;          // 16 KiB barrier
    const size_t NEED      = OFF_BAR + 16384ULL;

    if (ws_size >= NEED) {
        unsigned char* w = (unsigned char*)d_ws;
        unsigned short* x_hi  = (unsigned short*)(w + OFF_XHI);
        unsigned short* x_lo  = (unsigned short*)(w + OFF_XLO);
        unsigned short* Wpk   = (unsigned short*)(w + OFF_WPK);
        float*          bias  = (float*)(w + OFF_BIAS);
        unsigned short* hring = (unsigned short*)(w + OFF_HR);
        unsigned*       pdone = (unsigned*)(w + OFF_PD);
        unsigned*       bar   = (unsigned*)(w + OFF_BAR);

        hipLaunchKernelGGL(convert_split, dim3(4096), dim3(256), 0, stream,
                           input, x_hi, x_lo, T_STEPS * BH / 4);
        hipLaunchKernelGGL(pack_W, dim3(8192), dim3(256), 0, stream,
                           W_ih, W_hh, Wpk);
        hipLaunchKernelGGL(prep_state, dim3(128), dim3(256), 0, stream,
                           h0, b_ih, b_hh, hring + 2 * (size_t)BH, bias,
                           pdone, bar);

        (void)hipFuncSetAttribute(reinterpret_cast<const void*>(lstm_persistent),
                                  hipFuncAttributeMaxDynamicSharedMemorySize, 147456);
        hipLaunchKernelGGL(lstm_persistent, dim3(NBLK), dim3(512), 147456, stream,
                           x_hi, x_lo, Wpk, hring, bias, c0, out, pdone, bar);
    } else {
        // fallback: round-1 path (c scratch only)
        float* c_ws = (float*)d_ws;
        for (int t = T_STEPS - 1; t >= 0; --t) {
            const float* x_t = input + (size_t)t * BATCH * IN_DIM;
            const float* hp  = (t == T_STEPS - 1) ? h0 : out + (size_t)(t + 1) * BH;
            const float* cp  = (t == T_STEPS - 1) ? c0 : c_ws;
            hipLaunchKernelGGL(lstm_step_fused, dim3(128), dim3(256), 0, stream,
                               x_t, hp, cp, c_ws, out + (size_t)t * BH,
                               W_ih, W_hh, b_ih, b_hh);
        }
        hipLaunchKernelGGL(lstm_finalize, dim3(128), dim3(256), 0, stream,
                           out, c_ws,
                           out + (size_t)T_STEPS * BH,
                           out + (size_t)T_STEPS * BH + BH);
    }
}